// Round 16
// baseline (529.641 us; speedup 1.0000x reference)
//
#include <hip/hip_runtime.h>
#include <hip/hip_bf16.h>

typedef unsigned short u16;
typedef unsigned int u32;
typedef __bf16 bf16x8 __attribute__((ext_vector_type(8)));
typedef float f32x4 __attribute__((ext_vector_type(4)));
typedef u16 ushort8 __attribute__((ext_vector_type(8)));

#define TSEQ 2048
#define NHEAD 16

#define GLD16(gp, lp) __builtin_amdgcn_global_load_lds( \
    (__attribute__((address_space(1))) void*)(gp), \
    (__attribute__((address_space(3))) void*)(lp), 16, 0, 0)

static __device__ __forceinline__ float bf2f(u16 u) {
  unsigned int x = ((unsigned int)u) << 16;
  union { unsigned int i; float f; } c; c.i = x; return c.f;
}
static __device__ __forceinline__ u16 f2bf(float f) {
  union { float f; unsigned int i; } c; c.f = f;
  unsigned int x = c.i;
  unsigned int r = (x + 0x7FFFu + ((x >> 16) & 1u)) >> 16;
  return (u16)r;
}
static __device__ __forceinline__ void st_out(u16* p, float v) { *p = f2bf(v); }
static __device__ __forceinline__ void st_out(float* p, float v) { *p = v; }
static __device__ __forceinline__ u32 cvtpk(float lo, float hi) {
  u32 w;
  asm("v_cvt_pk_bf16_f32 %0, %1, %2" : "=v"(w) : "v"(lo), "v"(hi));
  return w;
}

// ---------------- convert x (f32 -> bf16), 8 elems/thread ----------------
__global__ __launch_bounds__(256) void k_conv_x(const float* __restrict__ x, u16* __restrict__ xb) {
  size_t i = ((size_t)blockIdx.x * 256 + threadIdx.x) * 8;
  float4 a = *(const float4*)(x + i);
  float4 b = *(const float4*)(x + i + 4);
  ushort8 o;
  o[0] = f2bf(a.x); o[1] = f2bf(a.y); o[2] = f2bf(a.z); o[3] = f2bf(a.w);
  o[4] = f2bf(b.x); o[5] = f2bf(b.y); o[6] = f2bf(b.z); o[7] = f2bf(b.w);
  *(ushort8*)(xb + i) = o;
}

// -------- ALL weight transposes in one dispatch: block-range switch --------
__global__ __launch_bounds__(256) void k_tconv_all(const float* __restrict__ w_dkv, const float* __restrict__ w_dq,
                                                   const float* __restrict__ w_kr, const float* __restrict__ w_ukv,
                                                   const float* __restrict__ w_q, const float* __restrict__ w_cp,
                                                   u16* __restrict__ wcatT, u16* __restrict__ wukvT,
                                                   u16* __restrict__ wqT, u16* __restrict__ wcpT) {
  __shared__ float sm[32][33];
  int z = blockIdx.x;
  const float* src; u16* dst; int R, Cc, Rpad, bx, by;
  if (z < 1536)       { src = w_dkv; dst = wcatT;              R = 2048; Cc = 672;  Rpad = 2048; int l = z;        bx = l % 64; by = l / 64; }
  else if (z < 3072)  { src = w_dq;  dst = wcatT + 768 * 2048; R = 2048; Cc = 672;  Rpad = 2048; int l = z - 1536; bx = l % 64; by = l / 64; }
  else if (z < 3200)  { src = w_kr;  dst = wcatT + 1536 * 2048;R = 2048; Cc = 64;   Rpad = 2048; int l = z - 3072; bx = l % 64; by = l / 64; }
  else if (z < 5504)  { src = w_ukv; dst = wukvT;              R = 672;  Cc = 3072; Rpad = 768;  int l = z - 3200; bx = l % 24; by = l / 24; }
  else if (z < 7040)  { src = w_q;   dst = wqT;                R = 672;  Cc = 2048; Rpad = 768;  int l = z - 5504; bx = l % 24; by = l / 24; }
  else                { src = w_cp;  dst = wcpT;               R = 2048; Cc = 2048; Rpad = 2048; int l = z - 7040; bx = l % 64; by = l / 64; }
  int tx = threadIdx.x & 31, ty = threadIdx.x >> 5;
  int r0 = bx * 32, c0 = by * 32;
#pragma unroll
  for (int i = 0; i < 4; i++) {
    int r = r0 + ty + 8 * i;
    int c = c0 + tx;
    sm[ty + 8 * i][tx] = (r < R && c < Cc) ? src[(size_t)r * Cc + c] : 0.f;
  }
  __syncthreads();
#pragma unroll
  for (int i = 0; i < 4; i++) {
    int c = c0 + ty + 8 * i;
    dst[(size_t)c * Rpad + r0 + tx] = f2bf(sm[tx][ty + 8 * i]);
  }
}

// ---------------- gate = 2*sigmoid(x[:, :32] @ w_ve_gate) ----------------
__global__ __launch_bounds__(256) void k_gate(const float* __restrict__ x, const float* __restrict__ wg,
                                              float* __restrict__ gate) {
  int idx = blockIdx.x * 256 + threadIdx.x; // m*16 + h
  int m = idx >> 4, h = idx & 15;
  const float* xr = x + (size_t)m * 2048;
  float s = 0.f;
#pragma unroll
  for (int j = 0; j < 32; j++) s += xr[j] * wg[j * 16 + h];
  gate[idx] = 2.f / (1.f + __expf(-s));
}

// ---------------- 128x128 GEMM, m97-style: linear LDS + global_load_lds w16, BK=32, strided ----------------
template <typename OT>
__global__ __launch_bounds__(256) void k_gemm128(const u16* __restrict__ A, int lda,
                                                 const u16* __restrict__ BT, int ldb,
                                                 OT* __restrict__ C, int ldc,
                                                 int K) {
  __shared__ __align__(16) u16 As[128 * 32];
  __shared__ __align__(16) u16 Bs[128 * 32];
  int t = threadIdx.x;
  int wid = t >> 6, lane = t & 63;
  int m0 = blockIdx.y * 128, n0 = blockIdx.x * 128;
  int c0 = wid * 2;
  int srow0 = c0 * 16 + (lane >> 2);
  int scol = (lane & 3) * 8;
  const u16* Ag0 = A + (size_t)(m0 + srow0) * lda + scol;
  const u16* Ag1 = A + (size_t)(m0 + srow0 + 16) * lda + scol;
  const u16* Bg0 = BT + (size_t)(n0 + srow0) * ldb + scol;
  const u16* Bg1 = BT + (size_t)(n0 + srow0 + 16) * ldb + scol;
  u16* Al0 = &As[c0 * 512];
  u16* Al1 = &As[c0 * 512 + 512];
  u16* Bl0 = &Bs[c0 * 512];
  u16* Bl1 = &Bs[c0 * 512 + 512];
  int wr = (wid >> 1) * 64, wc = (wid & 1) * 64;
  int fr = lane & 15, fo = (lane >> 4) * 8;
  f32x4 acc[4][4];
#pragma unroll
  for (int m = 0; m < 4; m++)
#pragma unroll
    for (int n = 0; n < 4; n++) acc[m][n] = (f32x4){0, 0, 0, 0};
  for (int k0 = 0; k0 < K; k0 += 32) {
    GLD16(Ag0 + k0, Al0);
    GLD16(Ag1 + k0, Al1);
    GLD16(Bg0 + k0, Bl0);
    GLD16(Bg1 + k0, Bl1);
    __syncthreads();
    bf16x8 af[4], bf[4];
#pragma unroll
    for (int m = 0; m < 4; m++) af[m] = *(const bf16x8*)&As[(wr + m * 16 + fr) * 32 + fo];
#pragma unroll
    for (int n = 0; n < 4; n++) bf[n] = *(const bf16x8*)&Bs[(wc + n * 16 + fr) * 32 + fo];
#pragma unroll
    for (int m = 0; m < 4; m++)
#pragma unroll
      for (int n = 0; n < 4; n++)
        acc[m][n] = __builtin_amdgcn_mfma_f32_16x16x32_bf16(af[m], bf[n], acc[m][n], 0, 0, 0);
    __syncthreads();
  }
  int cr = (lane >> 4) * 4, cc = lane & 15;
#pragma unroll
  for (int m = 0; m < 4; m++)
#pragma unroll
    for (int n = 0; n < 4; n++)
#pragma unroll
      for (int r = 0; r < 4; r++)
        st_out(&C[(size_t)(m0 + wr + m * 16 + cr + r) * ldc + n0 + wc + n * 16 + cc], acc[m][n][r]);
}

// ---------------- dual GEMM: blocks [0,24) -> kv; blocks [24,40) -> q with fused rope+rmsnorm -> qf ----------------
__global__ __launch_bounds__(256) void k_gemm_dual(const u16* __restrict__ catout,
                                                   const u16* __restrict__ wukvT,
                                                   u16* __restrict__ kvb,
                                                   const u16* __restrict__ wqT,
                                                   const float* __restrict__ cosp,
                                                   const float* __restrict__ sinp,
                                                   u16* __restrict__ qf) {
  __shared__ __align__(16) u16 As[128 * 32];
  __shared__ __align__(16) u16 Bs[128 * 32];
  int t = threadIdx.x;
  int wid = t >> 6, lane = t & 63;
  int bx = blockIdx.x;
  bool isq = (bx >= 24);
  int nx = isq ? bx - 24 : bx;
  int m0 = blockIdx.y * 128, n0 = nx * 128;
  const u16* A = isq ? catout + 768 : catout;
  const u16* BT = isq ? wqT : wukvT;
  int c0 = wid * 2;
  int srow0 = c0 * 16 + (lane >> 2);
  int scol = (lane & 3) * 8;
  const u16* Ag0 = A + (size_t)(m0 + srow0) * 1664 + scol;
  const u16* Ag1 = A + (size_t)(m0 + srow0 + 16) * 1664 + scol;
  const u16* Bg0 = BT + (size_t)(n0 + srow0) * 768 + scol;
  const u16* Bg1 = BT + (size_t)(n0 + srow0 + 16) * 768 + scol;
  u16* Al0 = &As[c0 * 512];
  u16* Al1 = &As[c0 * 512 + 512];
  u16* Bl0 = &Bs[c0 * 512];
  u16* Bl1 = &Bs[c0 * 512 + 512];
  int wr = (wid >> 1) * 64, wc = (wid & 1) * 64;
  int fr = lane & 15, fo = (lane >> 4) * 8;
  f32x4 acc[4][4];
#pragma unroll
  for (int m = 0; m < 4; m++)
#pragma unroll
    for (int n = 0; n < 4; n++) acc[m][n] = (f32x4){0, 0, 0, 0};
  for (int k0 = 0; k0 < 768; k0 += 32) {
    GLD16(Ag0 + k0, Al0);
    GLD16(Ag1 + k0, Al1);
    GLD16(Bg0 + k0, Bl0);
    GLD16(Bg1 + k0, Bl1);
    __syncthreads();
    bf16x8 af[4], bf[4];
#pragma unroll
    for (int m = 0; m < 4; m++) af[m] = *(const bf16x8*)&As[(wr + m * 16 + fr) * 32 + fo];
#pragma unroll
    for (int n = 0; n < 4; n++) bf[n] = *(const bf16x8*)&Bs[(wc + n * 16 + fr) * 32 + fo];
#pragma unroll
    for (int m = 0; m < 4; m++)
#pragma unroll
      for (int n = 0; n < 4; n++)
        acc[m][n] = __builtin_amdgcn_mfma_f32_16x16x32_bf16(af[m], bf[n], acc[m][n], 0, 0, 0);
    __syncthreads();
  }
  int cr = (lane >> 4) * 4, cc = lane & 15;
  if (!isq) {
#pragma unroll
    for (int m = 0; m < 4; m++)
#pragma unroll
      for (int n = 0; n < 4; n++)
#pragma unroll
        for (int r = 0; r < 4; r++)
          kvb[(size_t)(m0 + wr + m * 16 + cr + r) * 3072 + n0 + wc + n * 16 + cc] = f2bf(acc[m][n][r]);
    return;
  }
  int h = nx;
  int wch = wid & 1;
  int wrg = wid >> 1;
  if (wch == 1) {
#pragma unroll
    for (int m = 0; m < 4; m++)
#pragma unroll
      for (int r = 0; r < 4; r++) {
        int grow = m0 + wr + m * 16 + cr + r;
#pragma unroll
        for (int n = 0; n < 2; n++) {
          int i = n * 16 + cc;
          float cth = cosp[(size_t)grow * 32 + i];
          float sth = sinp[(size_t)grow * 32 + i];
          float x1 = acc[m][n][r], x2 = acc[m][n + 2][r];
          acc[m][n][r]     = x1 * cth + x2 * sth;
          acc[m][n + 2][r] = x2 * cth - x1 * sth;
        }
      }
  }
  float part[4][4];
#pragma unroll
  for (int m = 0; m < 4; m++)
#pragma unroll
    for (int r = 0; r < 4; r++) {
      float s2 = 0.f;
#pragma unroll
      for (int n = 0; n < 4; n++) s2 += acc[m][n][r] * acc[m][n][r];
#pragma unroll
      for (int o = 1; o < 16; o <<= 1) s2 += __shfl_xor(s2, o, 64);
      part[m][r] = s2;
    }
  float* xs = (float*)As;
  if (cc == 0) {
#pragma unroll
    for (int m = 0; m < 4; m++)
#pragma unroll
      for (int r = 0; r < 4; r++)
        xs[(wrg * 2 + wch) * 64 + m * 16 + cr + r] = part[m][r];
  }
  __syncthreads();
#pragma unroll
  for (int m = 0; m < 4; m++)
#pragma unroll
    for (int r = 0; r < 4; r++) {
      int lrow = m * 16 + cr + r;
      float tot = part[m][r] + xs[(wrg * 2 + (wch ^ 1)) * 64 + lrow];
      float rms = rsqrtf(tot * (1.f / 128.f) + 1.1920929e-7f) * 0.1275174245f;
      int grow = m0 + wr + lrow;
      int b2 = grow >> 11, tt = grow & 2047;
      size_t base = (((size_t)(b2 * NHEAD + h)) * TSEQ + tt) * 128 + wch * 64;
#pragma unroll
      for (int n = 0; n < 4; n++)
        qf[base + n * 16 + cc] = f2bf(acc[m][n][r] * rms);
    }
}

// ---------------- build K -> swizzled 8KB tile images ksw[bh][tile32][8KB] ----------------
// tile32 = 32 keys x 128 d; byte = (r32*256 + d*2) ^ ((r32&7)<<4). Block covers 64 rows = 2 tiles.
__global__ __launch_bounds__(256) void k_build_k(const u16* __restrict__ kv, const u16* __restrict__ kr,
                                                 const float* __restrict__ cosp, const float* __restrict__ sinp,
                                                 u16* __restrict__ ksw) {
  __shared__ __align__(16) u16 sm[8192];
  int tid = threadIdx.x, wid = tid >> 6, lane = tid & 63;
  int bh = blockIdx.x >> 5, tile = blockIdx.x & 31;
  int b = bh >> 4, h = bh & 15;
  int d0 = lane * 2;
  for (int rr = 0; rr < 16; rr++) {
    int row = wid * 16 + rr;
    int t = tile * 64 + row;
    int m = b * TSEQ + t;
    float v[2];
#pragma unroll
    for (int e = 0; e < 2; e++) {
      int d = d0 + e;
      float val;
      if (d < 64) {
        val = bf2f(kv[(size_t)m * 3072 + h * 192 + d]);
      } else {
        int dd = d - 64, i = dd & 31;
        float c = cosp[m * 32 + i], s = sinp[m * 32 + i];
        float x1 = bf2f(kr[(size_t)m * 1664 + i]), x2 = bf2f(kr[(size_t)m * 1664 + 32 + i]);
        val = (dd < 32) ? (x1 * c + x2 * s) : (x2 * c - x1 * s);
      }
      v[e] = val;
    }
    float ss = v[0] * v[0] + v[1] * v[1];
#pragma unroll
    for (int o = 1; o < 64; o <<= 1) ss += __shfl_xor(ss, o, 64);
    float rms = rsqrtf(ss * (1.f / 128.f) + 1.1920929e-7f);
    int a = ((row & 32) ? 8192 : 0) + (((row & 31) * 256 + d0 * 2) ^ ((row & 7) << 4));
    sm[a >> 1] = f2bf(v[0] * rms);
    sm[(a >> 1) + 1] = f2bf(v[1] * rms);
  }
  __syncthreads();
  u16* dst = ksw + ((size_t)(bh * 32 + tile)) * 8192 + tid * 32;
  const u16* src = sm + tid * 32;
#pragma unroll
  for (int j = 0; j < 4; j++)
    *(ushort8*)(dst + j * 8) = *(const ushort8*)(src + j * 8);
}

// ---------------- build V -> swizzled 8KB tile images vsw[bh][tile32][8KB] ----------------
// tile32 = 128 d x 32 t; byte = (d*64 + tloc*2) ^ ((d&7)<<4). Block covers 64 t = 2 tiles.
__global__ __launch_bounds__(256) void k_build_v(const u16* __restrict__ kv, const float* __restrict__ ve,
                                                 const float* __restrict__ gate, u16* __restrict__ vsw) {
  __shared__ __align__(16) char sm[128 * 128];
  int bh = blockIdx.x >> 5, tile = blockIdx.x & 31;
  int t0 = tile * 64;
  int b = bh >> 4, h = bh & 15;
  int tt = threadIdx.x >> 2, dp = (threadIdx.x & 3) * 32;
  int m = b * TSEQ + t0 + tt;
  float g = gate[m * 16 + h];
  const u16* kvp = kv + (size_t)m * 3072 + h * 192 + 64 + dp;
  const float* vep = ve + (size_t)m * 2048 + h * 128 + dp;
  ushort8 kvv[4];
  float4 vev[8];
#pragma unroll
  for (int u = 0; u < 4; u++) kvv[u] = *(const ushort8*)(kvp + u * 8);
#pragma unroll
  for (int u = 0; u < 8; u++) vev[u] = *(const float4*)(vep + u * 4);
  int half = (tt >> 5) * 8192, tloc = tt & 31;
#pragma unroll
  for (int j = 0; j < 32; j++) {
    float vvf = ((const float*)&vev[j >> 2])[j & 3];
    float v = bf2f(kvv[j >> 3][j & 7]) + g * vvf;
    int row = dp + j;
    int a = half + ((row * 64 + tloc * 2) ^ ((row & 7) << 4));
    *(u16*)(sm + a) = f2bf(v);
  }
  __syncthreads();
  u16* dst = vsw + ((size_t)(bh * 32 + tile)) * 8192 + threadIdx.x * 32;
  const u16* src = (const u16*)sm + threadIdx.x * 32;
#pragma unroll
  for (int j = 0; j < 4; j++)
    *(ushort8*)(dst + j * 8) = *(const ushort8*)(src + j * 8);
}

// ---------------- flash attention v5: KVBLK=32, LDS 40KB (4 blocks/CU), split-K for qb>=4 ----------------
__global__ __launch_bounds__(256, 4) void k_attn(const u16* __restrict__ qf, const u16* __restrict__ ksw,
                                                 const u16* __restrict__ vsw, u16* __restrict__ y,
                                                 float* __restrict__ opart, float* __restrict__ mpart,
                                                 float* __restrict__ lpart) {
  __shared__ __align__(16) u16 kvbuf[2][2][4096]; // [buf][K=0/V=1][8KB]
  __shared__ __align__(16) char plds_all[4][2048]; // per wave: P [32 q][32 k] bf16, XOR-swizzled
  int tid = threadIdx.x, wid = tid >> 6, lane = tid & 63;
  int gq = lane >> 4, c = lane & 15;
  // 896 blocks: per XCD 4 heads x 28 subtasks (24 split halves qb 15..4, 4 unsplit qb 3..0), heavy-first.
  int xcd = blockIdx.x & 7, idx = blockIdx.x >> 3; // idx 0..111
  int bh = xcd * 4 + (idx & 3);
  int sub = idx >> 2;                   // 0..27
  int qb, it0, it1, pidx = -1;
  if (sub < 24) {
    qb = 15 - (sub >> 1);
    int half = sub & 1;
    int nhalf = 2 * qb + 2;             // steps per half (of 4qb+4 total)
    it0 = half * nhalf;
    it1 = it0 + nhalf;
    pidx = bh * 24 + (qb - 4) * 2 + half;
  } else {
    qb = 27 - sub;                      // 3..0
    it0 = 0;
    it1 = 4 * qb + 4;
  }
  int q0w = qb * 128 + wid * 32;        // this wave's 32-row base
  const u16* qp = qf + (size_t)bh * TSEQ * 128;
  const u16* kswb = ksw + (size_t)bh * 32 * 8192; // 64 tiles x 4096 u16
  const u16* vswb = vsw + (size_t)bh * 32 * 8192;
  char* plds = plds_all[wid];
  int swz = (c & 7) << 4;
  bf16x8 qfr[2][4];
#pragma unroll
  for (int rg = 0; rg < 2; rg++)
#pragma unroll
    for (int kc = 0; kc < 4; kc++)
      qfr[rg][kc] = *(const bf16x8*)(qp + (size_t)(q0w + rg * 16 + c) * 128 + kc * 32 + gq * 8);
  f32x4 oacc[2][8];
#pragma unroll
  for (int rg = 0; rg < 2; rg++)
#pragma unroll
    for (int nd = 0; nd < 8; nd++) oacc[rg][nd] = (f32x4){0, 0, 0, 0};
  float mreg[2] = {-1e30f, -1e30f}, lreg[2] = {0.f, 0.f};
  int ch = wid * 2; // wave stages 1KB chunks ch, ch+1 of K and V (8 chunks per 8KB tile)
#pragma unroll
  for (int j = 0; j < 2; j++) {
    GLD16(kswb + (size_t)it0 * 4096 + (ch + j) * 512 + lane * 8, &kvbuf[0][0][(ch + j) * 512]);
    GLD16(vswb + (size_t)it0 * 4096 + (ch + j) * 512 + lane * 8, &kvbuf[0][1][(ch + j) * 512]);
  }
  __syncthreads();
  for (int it = it0; it < it1; it++) {
    int cur = (it - it0) & 1;
    if (it + 1 < it1) {
      const u16* kt = kswb + (size_t)(it + 1) * 4096;
      const u16* vt = vswb + (size_t)(it + 1) * 4096;
#pragma unroll
      for (int j = 0; j < 2; j++) {
        GLD16(kt + (ch + j) * 512 + lane * 8, &kvbuf[cur ^ 1][0][(ch + j) * 512]);
        GLD16(vt + (ch + j) * 512 + lane * 8, &kvbuf[cur ^ 1][1][(ch + j) * 512]);
      }
    }
    int kt0 = it * 32;
    if (kt0 <= q0w + 31) { // wave-uniform skip of fully-masked tiles
      const char* Kt = (const char*)kvbuf[cur][0];
      const char* Vt = (const char*)kvbuf[cur][1];
      bool maskit = (kt0 + 31 > q0w);
      f32x4 sacc[2][2];
#pragma unroll
      for (int rg = 0; rg < 2; rg++)
#pragma unroll
        for (int s = 0; s < 2; s++) sacc[rg][s] = (f32x4){0, 0, 0, 0};
#pragma unroll
      for (int s = 0; s < 2; s++) {
        int row = s * 16 + c;
#pragma unroll
        for (int kc = 0; kc < 4; kc++) {
          int a = (row * 256 + (kc * 32 + gq * 8) * 2) ^ ((row & 7) << 4);
          bf16x8 kfr = *(const bf16x8*)(Kt + a);
          sacc[0][s] = __builtin_amdgcn_mfma_f32_16x16x32_bf16(kfr, qfr[0][kc], sacc[0][s], 0, 0, 0);
          sacc[1][s] = __builtin_amdgcn_mfma_f32_16x16x32_bf16(kfr, qfr[1][kc], sacc[1][s], 0, 0, 0);
        }
      }
      if (maskit) {
#pragma unroll
        for (int rg = 0; rg < 2; rg++) {
          int qrow = q0w + rg * 16 + c;
#pragma unroll
          for (int s = 0; s < 2; s++)
#pragma unroll
            for (int r = 0; r < 4; r++) {
              int key = kt0 + s * 16 + gq * 4 + r;
              sacc[rg][s][r] = (key <= qrow) ? sacc[rg][s][r] : -3e38f;
            }
        }
      }
      float mx[2];
#pragma unroll
      for (int rg = 0; rg < 2; rg++) {
        float m2 = sacc[rg][0][0];
#pragma unroll
        for (int s = 0; s < 2; s++)
#pragma unroll
          for (int r = 0; r < 4; r++) m2 = fmaxf(m2, sacc[rg][s][r]);
        m2 = fmaxf(m2, __shfl_xor(m2, 16, 64));
        m2 = fmaxf(m2, __shfl_xor(m2, 32, 64));
        mx[rg] = m2;
      }
      bool ok = (mx[0] - mreg[0] <= 11.f) && (mx[1] - mreg[1] <= 11.f);
      if (!__all(ok)) {
#pragma unroll
        for (int rg = 0; rg < 2; rg++) {
          float mn = fmaxf(mreg[rg], mx[rg]);
          float fac = exp2f(mreg[rg] - mn);
          lreg[rg] *= fac;
          float fq[4];
#pragma unroll
          for (int r = 0; r < 4; r++) fq[r] = __shfl(fac, gq * 4 + r, 64);
#pragma unroll
          for (int nd = 0; nd < 8; nd++)
#pragma unroll
            for (int r = 0; r < 4; r++) oacc[rg][nd][r] *= fq[r];
          mreg[rg] = mn;
        }
      }
#pragma unroll
      for (int rg = 0; rg < 2; rg++) {
        float p[2][4];
        float rs = 0.f;
#pragma unroll
        for (int s = 0; s < 2; s++)
#pragma unroll
          for (int r = 0; r < 4; r++) {
            p[s][r] = exp2f(sacc[rg][s][r] - mreg[rg]);
            rs += p[s][r];
          }
        rs += __shfl_xor(rs, 16, 64);
        rs += __shfl_xor(rs, 32, 64);
        lreg[rg] += rs;
#pragma unroll
        for (int s = 0; s < 2; s++) {
          u32 w0 = cvtpk(p[s][0], p[s][1]);
          u32 w1 = cvtpk(p[s][2], p[s][3]);
          int a = (rg * 1024 + ((c * 64 + s * 32 + gq * 8) ^ swz));
          *(uint2*)(plds + a) = make_uint2(w0, w1);
        }
      }
      // PV: single K=32 step; V tile rows stride 64B
      {
        int a0 = (c * 64 + gq * 16) ^ swz;
        bf16x8 pa0 = *(const bf16x8*)(plds + a0);
        bf16x8 pa1 = *(const bf16x8*)(plds + 1024 + a0);
#pragma unroll
        for (int nd = 0; nd < 8; nd++) {
          int vrow = nd * 16 + c;
          int av = (vrow * 64 + gq * 16) ^ ((vrow & 7) << 4);
          bf16x8 vfr = *(const bf16x8*)(Vt + av);
          oacc[0][nd] = __builtin_amdgcn_mfma_f32_16x16x32_bf16(pa0, vfr, oacc[0][nd], 0, 0, 0);
          oacc[1][nd] = __builtin_amdgcn_mfma_f32_16x16x32_bf16(pa1, vfr, oacc[1][nd], 0, 0, 0);
        }
      }
    }
    __syncthreads();
  }
  if (pidx >= 0) {
    float* op = opart + (size_t)pidx * 16384;
#pragma unroll
    for (int rg = 0; rg < 2; rg++) {
#pragma unroll
      for (int nd = 0; nd < 8; nd++)
#pragma unroll
        for (int r = 0; r < 4; r++)
          op[(wid * 32 + rg * 16 + gq * 4 + r) * 128 + nd * 16 + c] = oacc[rg][nd][r];
      if (gq == 0) {
        mpart[pidx * 128 + wid * 32 + rg * 16 + c] = mreg[rg];
        lpart[pidx * 128 + wid * 32 + rg * 16 + c] = lreg[rg];
      }
    }
    return;
  }
  int b2 = bh >> 4, h2 = bh & 15;
#pragma unroll
  for (int rg = 0; rg < 2; rg++) {
    float linv = 1.f / lreg[rg];
    float inv[4];
#pragma unroll
    for (int r = 0; r < 4; r++) inv[r] = __shfl(linv, gq * 4 + r, 64);
#pragma unroll
    for (int nd = 0; nd < 8; nd++) {
#pragma unroll
      for (int r = 0; r < 4; r++) {
        size_t offo = ((size_t)(b2 * TSEQ + q0w + rg * 16 + gq * 4 + r)) * 2048 + h2 * 128 + nd * 16 + c;
        y[offo] = f2bf(oacc[rg][nd][r] * inv[r]);
      }
    }
  }
}

// ---------------- merge the two split halves for qb>=4 -> y ----------------
__global__ __launch_bounds__(256) void k_merge(const float* __restrict__ opart, const float* __restrict__ mpart,
                                               const float* __restrict__ lpart, u16* __restrict__ y) {
  int blk = blockIdx.x;                 // 0..383 = bh*12 + (qb-4)
  int bh = blk / 12, qq = blk % 12, qb = 4 + qq;
  int p0 = bh * 24 + qq * 2, p1 = p0 + 1;
  int b2 = bh >> 4, h2 = bh & 15;
  for (int e = threadIdx.x; e < 16384; e += 256) {
    int row = e >> 7, col = e & 127;
    float m0 = mpart[p0 * 128 + row], m1 = mpart[p1 * 128 + row];
    float mm = fmaxf(m0, m1);
    float e0 = exp2f(m0 - mm), e1 = exp2f(m1 - mm);
    float l = lpart[p0 * 128 + row] * e0 + lpart[p1 * 128 + row] * e1;
    float o = opart[(size_t)p0 * 16384 + row * 128 + col] * e0 +
              opart[(size_t)p1 * 16384 + row * 128 + col] * e1;
    y[((size_t)(b2 * TSEQ + qb * 128 + row)) * 2048 + h2 * 128 + col] = f2bf(o / l);
  }
}

extern "C" void kernel_launch(void* const* d_in, const int* in_sizes, int n_in,
                              void* d_out, int out_size, void* d_ws, size_t ws_size,
                              hipStream_t stream) {
  (void)in_sizes; (void)n_in; (void)out_size; (void)ws_size;
  const float* x      = (const float*)d_in[0];
  const float* ve     = (const float*)d_in[1];
  const float* cosp   = (const float*)d_in[2];
  const float* sinp   = (const float*)d_in[3];
  const float* w_dkv  = (const float*)d_in[4];
  const float* w_ukv  = (const float*)d_in[5];
  const float* w_kr   = (const float*)d_in[6];
  const float* w_dq   = (const float*)d_in[7];
  const float* w_q    = (const float*)d_in[8];
  const float* w_cp   = (const float*)d_in[9];
  const float* w_vg   = (const float*)d_in[10];
  float* out = (float*)d_out;   // reference output dtype is float32

  char* ws = (char*)d_ws;
  size_t off = 0;
  auto alloc = [&](size_t bytes) -> char* {
    char* p = ws + off;
    off += (bytes + 255) & ~(size_t)255;
    return p;
  };
  // live-through-attention buffers first, then a contiguous dead zone for partial aliasing
  u16* xb     = (u16*)alloc(4096ull * 2048 * 2);
  u16* wcpT   = (u16*)alloc(2048ull * 2048 * 2);
  float* gateb = (float*)alloc(4096ull * 16 * 4);
  u16* qfb    = (u16*)alloc(2ull * 16 * 2048 * 128 * 2);
  u16* kswb   = (u16*)alloc(32ull * 32 * 8192 * 2);
  u16* vswb   = (u16*)alloc(32ull * 32 * 8192 * 2);
  // ---- dead-at-attention zone (53.5MB contiguous) ----
  u16* wcatT  = (u16*)alloc(1664ull * 2048 * 2);  // rows: [0,768)=dkv, [768,1536)=dq, [1536,1600)=kr
  u16* wukvT  = (u16*)alloc(3072ull * 768 * 2);
  u16* wqT    = (u16*)alloc(2048ull * 768 * 2);
  u16* catout = (u16*)alloc(4096ull * 1664 * 2);  // cols: [0,768)=ckv, [768,1536)=q1, [1536,1600)=kr
  u16* kvb    = (u16*)alloc(4096ull * 3072 * 2);
  u16* yb = xb; // alias: x_bf dead after the cat GEMM
  // split-K partials alias the dead zone: opart 768*64KB = 48MB + m/l 768KB <= 53.5MB
  float* opart = (float*)wcatT;
  float* mpart = opart + 768 * 16384;
  float* lpart = mpart + 768 * 128;

  // 1. conversions (single fused tconv dispatch)
  k_conv_x<<<dim3(4096), dim3(256), 0, stream>>>(x, xb);
  k_tconv_all<<<dim3(11136), dim3(256), 0, stream>>>(w_dkv, w_dq, w_kr, w_ukv, w_q, w_cp,
                                                     wcatT, wukvT, wqT, wcpT);
  k_gate<<<dim3(256), dim3(256), 0, stream>>>(x, w_vg, gateb);

  // 2. projection GEMMs: cat (x-projections), then fused {ukv | q+build_q}
  k_gemm128<u16><<<dim3(13, 32), dim3(256), 0, stream>>>(xb, 2048, wcatT, 2048, catout, 1664, 2048);
  k_gemm_dual<<<dim3(40, 32), dim3(256), 0, stream>>>(catout, wukvT, kvb, wqT, cosp, sinp, qfb);

  // 3. build k/v (emit pre-swizzled 8KB tile images, 2 per block)
  k_build_k<<<dim3(1024), dim3(256), 0, stream>>>(kvb, catout + 1536, cosp, sinp, kswb);
  k_build_v<<<dim3(1024), dim3(256), 0, stream>>>(kvb, ve, gateb, vswb);

  // 4. attention: 896 blocks (KVBLK=32, 40KB LDS, split-K qb>=4), then merge
  k_attn<<<dim3(896), dim3(256), 0, stream>>>(qfb, kswb, vswb, yb, opart, mpart, lpart);
  k_merge<<<dim3(384), dim3(256), 0, stream>>>(opart, mpart, lpart, yb);

  // 5. output projection (f32 out -> d_out)
  k_gemm128<float><<<dim3(16, 32), dim3(256), 0, stream>>>(yb, 2048, wcpT, 2048, out, 2048, 2048);
}

// Round 17
// 329.989 us; speedup vs baseline: 1.6050x; 1.6050x over previous
//
#include <hip/hip_runtime.h>
#include <hip/hip_bf16.h>

typedef unsigned short u16;
typedef unsigned int u32;
typedef __bf16 bf16x8 __attribute__((ext_vector_type(8)));
typedef float f32x4 __attribute__((ext_vector_type(4)));
typedef u16 ushort8 __attribute__((ext_vector_type(8)));

#define TSEQ 2048
#define NHEAD 16

#define GLD16(gp, lp) __builtin_amdgcn_global_load_lds( \
    (__attribute__((address_space(1))) void*)(gp), \
    (__attribute__((address_space(3))) void*)(lp), 16, 0, 0)

static __device__ __forceinline__ float bf2f(u16 u) {
  unsigned int x = ((unsigned int)u) << 16;
  union { unsigned int i; float f; } c; c.i = x; return c.f;
}
static __device__ __forceinline__ u16 f2bf(float f) {
  union { float f; unsigned int i; } c; c.f = f;
  unsigned int x = c.i;
  unsigned int r = (x + 0x7FFFu + ((x >> 16) & 1u)) >> 16;
  return (u16)r;
}
static __device__ __forceinline__ void st_out(u16* p, float v) { *p = f2bf(v); }
static __device__ __forceinline__ void st_out(float* p, float v) { *p = v; }
static __device__ __forceinline__ u32 cvtpk(float lo, float hi) {
  u32 w;
  asm("v_cvt_pk_bf16_f32 %0, %1, %2" : "=v"(w) : "v"(lo), "v"(hi));
  return w;
}

// ---------------- convert x (f32 -> bf16), 8 elems/thread ----------------
__global__ __launch_bounds__(256) void k_conv_x(const float* __restrict__ x, u16* __restrict__ xb) {
  size_t i = ((size_t)blockIdx.x * 256 + threadIdx.x) * 8;
  float4 a = *(const float4*)(x + i);
  float4 b = *(const float4*)(x + i + 4);
  ushort8 o;
  o[0] = f2bf(a.x); o[1] = f2bf(a.y); o[2] = f2bf(a.z); o[3] = f2bf(a.w);
  o[4] = f2bf(b.x); o[5] = f2bf(b.y); o[6] = f2bf(b.z); o[7] = f2bf(b.w);
  *(ushort8*)(xb + i) = o;
}

// -------- ALL weight transposes in one dispatch: block-range switch --------
__global__ __launch_bounds__(256) void k_tconv_all(const float* __restrict__ w_dkv, const float* __restrict__ w_dq,
                                                   const float* __restrict__ w_kr, const float* __restrict__ w_ukv,
                                                   const float* __restrict__ w_q, const float* __restrict__ w_cp,
                                                   u16* __restrict__ wcatT, u16* __restrict__ wukvT,
                                                   u16* __restrict__ wqT, u16* __restrict__ wcpT) {
  __shared__ float sm[32][33];
  int z = blockIdx.x;
  const float* src; u16* dst; int R, Cc, Rpad, bx, by;
  if (z < 1536)       { src = w_dkv; dst = wcatT;              R = 2048; Cc = 672;  Rpad = 2048; int l = z;        bx = l % 64; by = l / 64; }
  else if (z < 3072)  { src = w_dq;  dst = wcatT + 768 * 2048; R = 2048; Cc = 672;  Rpad = 2048; int l = z - 1536; bx = l % 64; by = l / 64; }
  else if (z < 3200)  { src = w_kr;  dst = wcatT + 1536 * 2048;R = 2048; Cc = 64;   Rpad = 2048; int l = z - 3072; bx = l % 64; by = l / 64; }
  else if (z < 5504)  { src = w_ukv; dst = wukvT;              R = 672;  Cc = 3072; Rpad = 768;  int l = z - 3200; bx = l % 24; by = l / 24; }
  else if (z < 7040)  { src = w_q;   dst = wqT;                R = 672;  Cc = 2048; Rpad = 768;  int l = z - 5504; bx = l % 24; by = l / 24; }
  else                { src = w_cp;  dst = wcpT;               R = 2048; Cc = 2048; Rpad = 2048; int l = z - 7040; bx = l % 64; by = l / 64; }
  int tx = threadIdx.x & 31, ty = threadIdx.x >> 5;
  int r0 = bx * 32, c0 = by * 32;
#pragma unroll
  for (int i = 0; i < 4; i++) {
    int r = r0 + ty + 8 * i;
    int c = c0 + tx;
    sm[ty + 8 * i][tx] = (r < R && c < Cc) ? src[(size_t)r * Cc + c] : 0.f;
  }
  __syncthreads();
#pragma unroll
  for (int i = 0; i < 4; i++) {
    int c = c0 + ty + 8 * i;
    dst[(size_t)c * Rpad + r0 + tx] = f2bf(sm[tx][ty + 8 * i]);
  }
}

// ---------------- gate = 2*sigmoid(x[:, :32] @ w_ve_gate) ----------------
__global__ __launch_bounds__(256) void k_gate(const float* __restrict__ x, const float* __restrict__ wg,
                                              float* __restrict__ gate) {
  int idx = blockIdx.x * 256 + threadIdx.x; // m*16 + h
  int m = idx >> 4, h = idx & 15;
  const float* xr = x + (size_t)m * 2048;
  float s = 0.f;
#pragma unroll
  for (int j = 0; j < 32; j++) s += xr[j] * wg[j * 16 + h];
  gate[idx] = 2.f / (1.f + __expf(-s));
}

// ---------------- 128x128 GEMM, m97-style: linear LDS + global_load_lds w16, BK=32, strided ----------------
template <typename OT>
__global__ __launch_bounds__(256) void k_gemm128(const u16* __restrict__ A, int lda,
                                                 const u16* __restrict__ BT, int ldb,
                                                 OT* __restrict__ C, int ldc,
                                                 int K) {
  __shared__ __align__(16) u16 As[128 * 32];
  __shared__ __align__(16) u16 Bs[128 * 32];
  int t = threadIdx.x;
  int wid = t >> 6, lane = t & 63;
  int m0 = blockIdx.y * 128, n0 = blockIdx.x * 128;
  int c0 = wid * 2;
  int srow0 = c0 * 16 + (lane >> 2);
  int scol = (lane & 3) * 8;
  const u16* Ag0 = A + (size_t)(m0 + srow0) * lda + scol;
  const u16* Ag1 = A + (size_t)(m0 + srow0 + 16) * lda + scol;
  const u16* Bg0 = BT + (size_t)(n0 + srow0) * ldb + scol;
  const u16* Bg1 = BT + (size_t)(n0 + srow0 + 16) * ldb + scol;
  u16* Al0 = &As[c0 * 512];
  u16* Al1 = &As[c0 * 512 + 512];
  u16* Bl0 = &Bs[c0 * 512];
  u16* Bl1 = &Bs[c0 * 512 + 512];
  int wr = (wid >> 1) * 64, wc = (wid & 1) * 64;
  int fr = lane & 15, fo = (lane >> 4) * 8;
  f32x4 acc[4][4];
#pragma unroll
  for (int m = 0; m < 4; m++)
#pragma unroll
    for (int n = 0; n < 4; n++) acc[m][n] = (f32x4){0, 0, 0, 0};
  for (int k0 = 0; k0 < K; k0 += 32) {
    GLD16(Ag0 + k0, Al0);
    GLD16(Ag1 + k0, Al1);
    GLD16(Bg0 + k0, Bl0);
    GLD16(Bg1 + k0, Bl1);
    __syncthreads();
    bf16x8 af[4], bf[4];
#pragma unroll
    for (int m = 0; m < 4; m++) af[m] = *(const bf16x8*)&As[(wr + m * 16 + fr) * 32 + fo];
#pragma unroll
    for (int n = 0; n < 4; n++) bf[n] = *(const bf16x8*)&Bs[(wc + n * 16 + fr) * 32 + fo];
#pragma unroll
    for (int m = 0; m < 4; m++)
#pragma unroll
      for (int n = 0; n < 4; n++)
        acc[m][n] = __builtin_amdgcn_mfma_f32_16x16x32_bf16(af[m], bf[n], acc[m][n], 0, 0, 0);
    __syncthreads();
  }
  int cr = (lane >> 4) * 4, cc = lane & 15;
#pragma unroll
  for (int m = 0; m < 4; m++)
#pragma unroll
    for (int n = 0; n < 4; n++)
#pragma unroll
      for (int r = 0; r < 4; r++)
        st_out(&C[(size_t)(m0 + wr + m * 16 + cr + r) * ldc + n0 + wc + n * 16 + cc], acc[m][n][r]);
}

// ---------------- dual GEMM: blocks [0,24) -> kv; blocks [24,40) -> q with fused rope+rmsnorm -> qf ----------------
__global__ __launch_bounds__(256) void k_gemm_dual(const u16* __restrict__ catout,
                                                   const u16* __restrict__ wukvT,
                                                   u16* __restrict__ kvb,
                                                   const u16* __restrict__ wqT,
                                                   const float* __restrict__ cosp,
                                                   const float* __restrict__ sinp,
                                                   u16* __restrict__ qf) {
  __shared__ __align__(16) u16 As[128 * 32];
  __shared__ __align__(16) u16 Bs[128 * 32];
  int t = threadIdx.x;
  int wid = t >> 6, lane = t & 63;
  int bx = blockIdx.x;
  bool isq = (bx >= 24);
  int nx = isq ? bx - 24 : bx;
  int m0 = blockIdx.y * 128, n0 = nx * 128;
  const u16* A = isq ? catout + 768 : catout;
  const u16* BT = isq ? wqT : wukvT;
  int c0 = wid * 2;
  int srow0 = c0 * 16 + (lane >> 2);
  int scol = (lane & 3) * 8;
  const u16* Ag0 = A + (size_t)(m0 + srow0) * 1664 + scol;
  const u16* Ag1 = A + (size_t)(m0 + srow0 + 16) * 1664 + scol;
  const u16* Bg0 = BT + (size_t)(n0 + srow0) * 768 + scol;
  const u16* Bg1 = BT + (size_t)(n0 + srow0 + 16) * 768 + scol;
  u16* Al0 = &As[c0 * 512];
  u16* Al1 = &As[c0 * 512 + 512];
  u16* Bl0 = &Bs[c0 * 512];
  u16* Bl1 = &Bs[c0 * 512 + 512];
  int wr = (wid >> 1) * 64, wc = (wid & 1) * 64;
  int fr = lane & 15, fo = (lane >> 4) * 8;
  f32x4 acc[4][4];
#pragma unroll
  for (int m = 0; m < 4; m++)
#pragma unroll
    for (int n = 0; n < 4; n++) acc[m][n] = (f32x4){0, 0, 0, 0};
  for (int k0 = 0; k0 < 768; k0 += 32) {
    GLD16(Ag0 + k0, Al0);
    GLD16(Ag1 + k0, Al1);
    GLD16(Bg0 + k0, Bl0);
    GLD16(Bg1 + k0, Bl1);
    __syncthreads();
    bf16x8 af[4], bf[4];
#pragma unroll
    for (int m = 0; m < 4; m++) af[m] = *(const bf16x8*)&As[(wr + m * 16 + fr) * 32 + fo];
#pragma unroll
    for (int n = 0; n < 4; n++) bf[n] = *(const bf16x8*)&Bs[(wc + n * 16 + fr) * 32 + fo];
#pragma unroll
    for (int m = 0; m < 4; m++)
#pragma unroll
      for (int n = 0; n < 4; n++)
        acc[m][n] = __builtin_amdgcn_mfma_f32_16x16x32_bf16(af[m], bf[n], acc[m][n], 0, 0, 0);
    __syncthreads();
  }
  int cr = (lane >> 4) * 4, cc = lane & 15;
  if (!isq) {
#pragma unroll
    for (int m = 0; m < 4; m++)
#pragma unroll
      for (int n = 0; n < 4; n++)
#pragma unroll
        for (int r = 0; r < 4; r++)
          kvb[(size_t)(m0 + wr + m * 16 + cr + r) * 3072 + n0 + wc + n * 16 + cc] = f2bf(acc[m][n][r]);
    return;
  }
  int h = nx;
  int wch = wid & 1;
  int wrg = wid >> 1;
  if (wch == 1) {
#pragma unroll
    for (int m = 0; m < 4; m++)
#pragma unroll
      for (int r = 0; r < 4; r++) {
        int grow = m0 + wr + m * 16 + cr + r;
#pragma unroll
        for (int n = 0; n < 2; n++) {
          int i = n * 16 + cc;
          float cth = cosp[(size_t)grow * 32 + i];
          float sth = sinp[(size_t)grow * 32 + i];
          float x1 = acc[m][n][r], x2 = acc[m][n + 2][r];
          acc[m][n][r]     = x1 * cth + x2 * sth;
          acc[m][n + 2][r] = x2 * cth - x1 * sth;
        }
      }
  }
  float part[4][4];
#pragma unroll
  for (int m = 0; m < 4; m++)
#pragma unroll
    for (int r = 0; r < 4; r++) {
      float s2 = 0.f;
#pragma unroll
      for (int n = 0; n < 4; n++) s2 += acc[m][n][r] * acc[m][n][r];
#pragma unroll
      for (int o = 1; o < 16; o <<= 1) s2 += __shfl_xor(s2, o, 64);
      part[m][r] = s2;
    }
  float* xs = (float*)As;
  if (cc == 0) {
#pragma unroll
    for (int m = 0; m < 4; m++)
#pragma unroll
      for (int r = 0; r < 4; r++)
        xs[(wrg * 2 + wch) * 64 + m * 16 + cr + r] = part[m][r];
  }
  __syncthreads();
#pragma unroll
  for (int m = 0; m < 4; m++)
#pragma unroll
    for (int r = 0; r < 4; r++) {
      int lrow = m * 16 + cr + r;
      float tot = part[m][r] + xs[(wrg * 2 + (wch ^ 1)) * 64 + lrow];
      float rms = rsqrtf(tot * (1.f / 128.f) + 1.1920929e-7f) * 0.1275174245f;
      int grow = m0 + wr + lrow;
      int b2 = grow >> 11, tt = grow & 2047;
      size_t base = (((size_t)(b2 * NHEAD + h)) * TSEQ + tt) * 128 + wch * 64;
#pragma unroll
      for (int n = 0; n < 4; n++)
        qf[base + n * 16 + cc] = f2bf(acc[m][n][r] * rms);
    }
}

// ---------------- build K -> swizzled tile images ksw[bh][tile][16KB] ----------------
__global__ __launch_bounds__(256) void k_build_k(const u16* __restrict__ kv, const u16* __restrict__ kr,
                                                 const float* __restrict__ cosp, const float* __restrict__ sinp,
                                                 u16* __restrict__ ksw) {
  __shared__ __align__(16) u16 sm[8192];
  int tid = threadIdx.x, wid = tid >> 6, lane = tid & 63;
  int bh = blockIdx.x >> 5, tile = blockIdx.x & 31;
  int b = bh >> 4, h = bh & 15;
  int d0 = lane * 2;
  for (int rr = 0; rr < 16; rr++) {
    int row = wid * 16 + rr;
    int t = tile * 64 + row;
    int m = b * TSEQ + t;
    float v[2];
#pragma unroll
    for (int e = 0; e < 2; e++) {
      int d = d0 + e;
      float val;
      if (d < 64) {
        val = bf2f(kv[(size_t)m * 3072 + h * 192 + d]);
      } else {
        int dd = d - 64, i = dd & 31;
        float c = cosp[m * 32 + i], s = sinp[m * 32 + i];
        float x1 = bf2f(kr[(size_t)m * 1664 + i]), x2 = bf2f(kr[(size_t)m * 1664 + 32 + i]);
        val = (dd < 32) ? (x1 * c + x2 * s) : (x2 * c - x1 * s);
      }
      v[e] = val;
    }
    float ss = v[0] * v[0] + v[1] * v[1];
#pragma unroll
    for (int o = 1; o < 64; o <<= 1) ss += __shfl_xor(ss, o, 64);
    float rms = rsqrtf(ss * (1.f / 128.f) + 1.1920929e-7f);
    int a = (row * 256 + d0 * 2) ^ ((row & 7) << 4);
    sm[a >> 1] = f2bf(v[0] * rms);
    sm[(a >> 1) + 1] = f2bf(v[1] * rms);
  }
  __syncthreads();
  u16* dst = ksw + ((size_t)(bh * 32 + tile)) * 8192 + tid * 32;
  const u16* src = sm + tid * 32;
#pragma unroll
  for (int j = 0; j < 4; j++)
    *(ushort8*)(dst + j * 8) = *(const ushort8*)(src + j * 8);
}

// ---------------- build V -> swizzled tile images vsw[bh][tile][16KB] ----------------
__global__ __launch_bounds__(256) void k_build_v(const u16* __restrict__ kv, const float* __restrict__ ve,
                                                 const float* __restrict__ gate, u16* __restrict__ vsw) {
  __shared__ __align__(16) char sm[128 * 128];
  int bh = blockIdx.x >> 5, tile = blockIdx.x & 31;
  int t0 = tile * 64;
  int b = bh >> 4, h = bh & 15;
  int tt = threadIdx.x >> 2, dp = (threadIdx.x & 3) * 32;
  int m = b * TSEQ + t0 + tt;
  float g = gate[m * 16 + h];
  const u16* kvp = kv + (size_t)m * 3072 + h * 192 + 64 + dp;
  const float* vep = ve + (size_t)m * 2048 + h * 128 + dp;
  ushort8 kvv[4];
  float4 vev[8];
#pragma unroll
  for (int u = 0; u < 4; u++) kvv[u] = *(const ushort8*)(kvp + u * 8);
#pragma unroll
  for (int u = 0; u < 8; u++) vev[u] = *(const float4*)(vep + u * 4);
#pragma unroll
  for (int j = 0; j < 32; j++) {
    float vvf = ((const float*)&vev[j >> 2])[j & 3];
    float v = bf2f(kvv[j >> 3][j & 7]) + g * vvf;
    int row = dp + j;
    int a = row * 128 + tt * 2;
    *(u16*)(sm + (a ^ ((row & 7) << 4))) = f2bf(v);
  }
  __syncthreads();
  u16* dst = vsw + ((size_t)(bh * 32 + tile)) * 8192 + threadIdx.x * 32;
  const u16* src = (const u16*)sm + threadIdx.x * 32;
#pragma unroll
  for (int j = 0; j < 4; j++)
    *(ushort8*)(dst + j * 8) = *(const ushort8*)(src + j * 8);
}

// ---------------- flash attention v2 (round-12/14): 128-row blocks, 32 q-rows/wave, staged K/V, balanced qb ----------------
__global__ __launch_bounds__(256, 2) void k_attn(const u16* __restrict__ qf, const u16* __restrict__ ksw,
                                                 const u16* __restrict__ vsw, u16* __restrict__ y) {
  __shared__ __align__(16) u16 kvbuf[2][2][8192]; // [buf][K=0/V=1][16KB]
  __shared__ __align__(16) char plds_all[4][4096]; // per wave: P [32 q][64 k] bf16, XOR-swizzled
  int tid = threadIdx.x, wid = tid >> 6, lane = tid & 63;
  int gq = lane >> 4, c = lane & 15;
  int task = (blockIdx.x & 7) * 64 + (blockIdx.x >> 3); // 512 blocks, XCD-chunked
  int bh = task >> 4;
  int tq = task & 15;
  int qb = ((task >> 5) & 1) ? tq : 15 - tq; // complementary pairing: blocks i,i+256 -> qb x,15-x (same CU)
  int nt = 2 * qb + 2;
  int q0w = qb * 128 + wid * 32;        // this wave's 32-row base
  const u16* qp = qf + (size_t)bh * TSEQ * 128;
  const u16* kswb = ksw + (size_t)bh * 32 * 8192;
  const u16* vswb = vsw + (size_t)bh * 32 * 8192;
  char* plds = plds_all[wid];
  int swz = (c & 7) << 4;
  bf16x8 qfr[2][4];
#pragma unroll
  for (int rg = 0; rg < 2; rg++)
#pragma unroll
    for (int kc = 0; kc < 4; kc++)
      qfr[rg][kc] = *(const bf16x8*)(qp + (size_t)(q0w + rg * 16 + c) * 128 + kc * 32 + gq * 8);
  f32x4 oacc[2][8];
#pragma unroll
  for (int rg = 0; rg < 2; rg++)
#pragma unroll
    for (int nd = 0; nd < 8; nd++) oacc[rg][nd] = (f32x4){0, 0, 0, 0};
  float mreg[2] = {-1e30f, -1e30f}, lreg[2] = {0.f, 0.f};
  int chunk = wid * 4;
#pragma unroll
  for (int j = 0; j < 4; j++) {
    GLD16(kswb + (chunk + j) * 512 + lane * 8, &kvbuf[0][0][(chunk + j) * 512]);
    GLD16(vswb + (chunk + j) * 512 + lane * 8, &kvbuf[0][1][(chunk + j) * 512]);
  }
  __syncthreads();
  for (int it = 0; it < nt; it++) {
    int cur = it & 1;
    if (it + 1 < nt) {
      const u16* kt = kswb + (size_t)(it + 1) * 8192;
      const u16* vt = vswb + (size_t)(it + 1) * 8192;
#pragma unroll
      for (int j = 0; j < 4; j++) {
        GLD16(kt + (chunk + j) * 512 + lane * 8, &kvbuf[cur ^ 1][0][(chunk + j) * 512]);
        GLD16(vt + (chunk + j) * 512 + lane * 8, &kvbuf[cur ^ 1][1][(chunk + j) * 512]);
      }
    }
    int kt0 = it * 64;
    if (kt0 <= q0w + 31) { // wave-uniform skip of fully-masked tiles
      const char* Kt = (const char*)kvbuf[cur][0];
      const char* Vt = (const char*)kvbuf[cur][1];
      bool maskit = (kt0 + 63 > q0w);
      f32x4 sacc[2][4];
#pragma unroll
      for (int rg = 0; rg < 2; rg++)
#pragma unroll
        for (int s = 0; s < 4; s++) sacc[rg][s] = (f32x4){0, 0, 0, 0};
#pragma unroll
      for (int s = 0; s < 4; s++) {
        int row = s * 16 + c;
#pragma unroll
        for (int kc = 0; kc < 4; kc++) {
          int a = (row * 256 + (kc * 32 + gq * 8) * 2) ^ ((row & 7) << 4);
          bf16x8 kfr = *(const bf16x8*)(Kt + a);
          sacc[0][s] = __builtin_amdgcn_mfma_f32_16x16x32_bf16(kfr, qfr[0][kc], sacc[0][s], 0, 0, 0);
          sacc[1][s] = __builtin_amdgcn_mfma_f32_16x16x32_bf16(kfr, qfr[1][kc], sacc[1][s], 0, 0, 0);
        }
      }
      if (maskit) {
#pragma unroll
        for (int rg = 0; rg < 2; rg++) {
          int qrow = q0w + rg * 16 + c;
#pragma unroll
          for (int s = 0; s < 4; s++)
#pragma unroll
            for (int r = 0; r < 4; r++) {
              int key = kt0 + s * 16 + gq * 4 + r;
              sacc[rg][s][r] = (key <= qrow) ? sacc[rg][s][r] : -3e38f;
            }
        }
      }
      float mx[2];
#pragma unroll
      for (int rg = 0; rg < 2; rg++) {
        float m2 = sacc[rg][0][0];
#pragma unroll
        for (int s = 0; s < 4; s++)
#pragma unroll
          for (int r = 0; r < 4; r++) m2 = fmaxf(m2, sacc[rg][s][r]);
        m2 = fmaxf(m2, __shfl_xor(m2, 16, 64));
        m2 = fmaxf(m2, __shfl_xor(m2, 32, 64));
        mx[rg] = m2;
      }
      bool ok = (mx[0] - mreg[0] <= 11.f) && (mx[1] - mreg[1] <= 11.f);
      if (!__all(ok)) {
#pragma unroll
        for (int rg = 0; rg < 2; rg++) {
          float mn = fmaxf(mreg[rg], mx[rg]);
          float fac = exp2f(mreg[rg] - mn);
          lreg[rg] *= fac;
          float fq[4];
#pragma unroll
          for (int r = 0; r < 4; r++) fq[r] = __shfl(fac, gq * 4 + r, 64);
#pragma unroll
          for (int nd = 0; nd < 8; nd++)
#pragma unroll
            for (int r = 0; r < 4; r++) oacc[rg][nd][r] *= fq[r];
          mreg[rg] = mn;
        }
      }
#pragma unroll
      for (int rg = 0; rg < 2; rg++) {
        float p[4][4];
        float rs = 0.f;
#pragma unroll
        for (int s = 0; s < 4; s++)
#pragma unroll
          for (int r = 0; r < 4; r++) {
            p[s][r] = exp2f(sacc[rg][s][r] - mreg[rg]);
            rs += p[s][r];
          }
        rs += __shfl_xor(rs, 16, 64);
        rs += __shfl_xor(rs, 32, 64);
        lreg[rg] += rs;
#pragma unroll
        for (int s = 0; s < 4; s++) {
          u32 w0 = cvtpk(p[s][0], p[s][1]);
          u32 w1 = cvtpk(p[s][2], p[s][3]);
          int a = (rg * 2048 + c * 128 + s * 32 + gq * 8) ^ swz;
          *(uint2*)(plds + a) = make_uint2(w0, w1);
        }
      }
#pragma unroll
      for (int kc2 = 0; kc2 < 2; kc2++) {
        int a0 = (c * 128 + kc2 * 64 + gq * 16) ^ swz;
        bf16x8 pa0 = *(const bf16x8*)(plds + a0);
        bf16x8 pa1 = *(const bf16x8*)(plds + 2048 + a0);
#pragma unroll
        for (int nd = 0; nd < 8; nd++) {
          int vrow = nd * 16 + c;
          int av = (vrow * 128 + (kc2 * 32 + gq * 8) * 2) ^ ((vrow & 7) << 4);
          bf16x8 vfr = *(const bf16x8*)(Vt + av);
          oacc[0][nd] = __builtin_amdgcn_mfma_f32_16x16x32_bf16(pa0, vfr, oacc[0][nd], 0, 0, 0);
          oacc[1][nd] = __builtin_amdgcn_mfma_f32_16x16x32_bf16(pa1, vfr, oacc[1][nd], 0, 0, 0);
        }
      }
    }
    __syncthreads();
  }
  int b2 = bh >> 4, h2 = bh & 15;
#pragma unroll
  for (int rg = 0; rg < 2; rg++) {
    float linv = 1.f / lreg[rg];
    float inv[4];
#pragma unroll
    for (int r = 0; r < 4; r++) inv[r] = __shfl(linv, gq * 4 + r, 64);
#pragma unroll
    for (int nd = 0; nd < 8; nd++) {
#pragma unroll
      for (int r = 0; r < 4; r++) {
        size_t offo = ((size_t)(b2 * TSEQ + q0w + rg * 16 + gq * 4 + r)) * 2048 + h2 * 128 + nd * 16 + c;
        y[offo] = f2bf(oacc[rg][nd][r] * inv[r]);
      }
    }
  }
}

extern "C" void kernel_launch(void* const* d_in, const int* in_sizes, int n_in,
                              void* d_out, int out_size, void* d_ws, size_t ws_size,
                              hipStream_t stream) {
  (void)in_sizes; (void)n_in; (void)out_size; (void)ws_size;
  const float* x      = (const float*)d_in[0];
  const float* ve     = (const float*)d_in[1];
  const float* cosp   = (const float*)d_in[2];
  const float* sinp   = (const float*)d_in[3];
  const float* w_dkv  = (const float*)d_in[4];
  const float* w_ukv  = (const float*)d_in[5];
  const float* w_kr   = (const float*)d_in[6];
  const float* w_dq   = (const float*)d_in[7];
  const float* w_q    = (const float*)d_in[8];
  const float* w_cp   = (const float*)d_in[9];
  const float* w_vg   = (const float*)d_in[10];
  float* out = (float*)d_out;   // reference output dtype is float32

  char* ws = (char*)d_ws;
  size_t off = 0;
  auto alloc = [&](size_t bytes) -> char* {
    char* p = ws + off;
    off += (bytes + 255) & ~(size_t)255;
    return p;
  };
  u16* xb     = (u16*)alloc(4096ull * 2048 * 2);
  u16* wcatT  = (u16*)alloc(1664ull * 2048 * 2);  // rows: [0,768)=dkv, [768,1536)=dq, [1536,1600)=kr
  u16* wukvT  = (u16*)alloc(3072ull * 768 * 2);
  u16* wqT    = (u16*)alloc(2048ull * 768 * 2);
  u16* wcpT   = (u16*)alloc(2048ull * 2048 * 2);
  u16* catout = (u16*)alloc(4096ull * 1664 * 2);  // cols: [0,768)=ckv, [768,1536)=q1, [1536,1600)=kr
  u16* kvb    = (u16*)alloc(4096ull * 3072 * 2);
  float* gateb = (float*)alloc(4096ull * 16 * 4);
  u16* qfb    = (u16*)alloc(2ull * 16 * 2048 * 128 * 2);
  u16* kswb   = (u16*)alloc(32ull * 32 * 8192 * 2);
  u16* vswb   = (u16*)alloc(32ull * 32 * 8192 * 2);
  u16* yb = xb; // alias: x_bf dead after the cat GEMM

  // 1. conversions (single fused tconv dispatch)
  k_conv_x<<<dim3(4096), dim3(256), 0, stream>>>(x, xb);
  k_tconv_all<<<dim3(11136), dim3(256), 0, stream>>>(w_dkv, w_dq, w_kr, w_ukv, w_q, w_cp,
                                                     wcatT, wukvT, wqT, wcpT);
  k_gate<<<dim3(256), dim3(256), 0, stream>>>(x, w_vg, gateb);

  // 2. projection GEMMs: cat (x-projections), then fused {ukv | q+build_q}
  k_gemm128<u16><<<dim3(13, 32), dim3(256), 0, stream>>>(xb, 2048, wcatT, 2048, catout, 1664, 2048);
  k_gemm_dual<<<dim3(40, 32), dim3(256), 0, stream>>>(catout, wukvT, kvb, wqT, cosp, sinp, qfb);

  // 3. build k/v (emit pre-swizzled 16KB tile images)
  k_build_k<<<dim3(1024), dim3(256), 0, stream>>>(kvb, catout + 1536, cosp, sinp, kswb);
  k_build_v<<<dim3(1024), dim3(256), 0, stream>>>(kvb, ve, gateb, vswb);

  // 4. attention -> y (aliases xb): 512 blocks x 4 waves x 32 rows/wave, CU-balanced
  k_attn<<<dim3(512), dim3(256), 0, stream>>>(qfb, kswb, vswb, yb);

  // 5. output projection (f32 out -> d_out)
  k_gemm128<float><<<dim3(16, 32), dim3(256), 0, stream>>>(yb, 2048, wcpT, 2048, out, 2048, 2048);
}

// Round 18
// 317.192 us; speedup vs baseline: 1.6698x; 1.0403x over previous
//
#include <hip/hip_runtime.h>
#include <hip/hip_bf16.h>

typedef unsigned short u16;
typedef unsigned int u32;
typedef __bf16 bf16x8 __attribute__((ext_vector_type(8)));
typedef float f32x4 __attribute__((ext_vector_type(4)));
typedef u16 ushort8 __attribute__((ext_vector_type(8)));

#define TSEQ 2048
#define NHEAD 16

#define GLD16(gp, lp) __builtin_amdgcn_global_load_lds( \
    (__attribute__((address_space(1))) void*)(gp), \
    (__attribute__((address_space(3))) void*)(lp), 16, 0, 0)

static __device__ __forceinline__ float bf2f(u16 u) {
  unsigned int x = ((unsigned int)u) << 16;
  union { unsigned int i; float f; } c; c.i = x; return c.f;
}
static __device__ __forceinline__ u16 f2bf(float f) {
  union { float f; unsigned int i; } c; c.f = f;
  unsigned int x = c.i;
  unsigned int r = (x + 0x7FFFu + ((x >> 16) & 1u)) >> 16;
  return (u16)r;
}
static __device__ __forceinline__ void st_out(u16* p, float v) { *p = f2bf(v); }
static __device__ __forceinline__ void st_out(float* p, float v) { *p = v; }
static __device__ __forceinline__ u32 cvtpk(float lo, float hi) {
  u32 w;
  asm("v_cvt_pk_bf16_f32 %0, %1, %2" : "=v"(w) : "v"(lo), "v"(hi));
  return w;
}

// -------- PREP: all weight transposes + x conversion + gate in ONE dispatch (block-range switch) --------
__global__ __launch_bounds__(256) void k_prep(const float* __restrict__ x,
                                              const float* __restrict__ w_dkv, const float* __restrict__ w_dq,
                                              const float* __restrict__ w_kr, const float* __restrict__ w_ukv,
                                              const float* __restrict__ w_q, const float* __restrict__ w_cp,
                                              const float* __restrict__ w_vg,
                                              u16* __restrict__ xb,
                                              u16* __restrict__ wcatT, u16* __restrict__ wukvT,
                                              u16* __restrict__ wqT, u16* __restrict__ wcpT,
                                              float* __restrict__ gateb) {
  __shared__ float sm[32][33];
  int z = blockIdx.x;
  if (z >= 15232) { // ---- gate: 256 blocks ----
    int idx = (z - 15232) * 256 + threadIdx.x; // m*16 + h
    int m = idx >> 4, h = idx & 15;
    const float* xr = x + (size_t)m * 2048;
    float s = 0.f;
#pragma unroll
    for (int j = 0; j < 32; j++) s += xr[j] * w_vg[j * 16 + h];
    gateb[idx] = 2.f / (1.f + __expf(-s));
    return;
  }
  if (z >= 11136) { // ---- conv_x: 4096 blocks ----
    size_t i = ((size_t)(z - 11136) * 256 + threadIdx.x) * 8;
    float4 a = *(const float4*)(x + i);
    float4 b = *(const float4*)(x + i + 4);
    ushort8 o;
    o[0] = f2bf(a.x); o[1] = f2bf(a.y); o[2] = f2bf(a.z); o[3] = f2bf(a.w);
    o[4] = f2bf(b.x); o[5] = f2bf(b.y); o[6] = f2bf(b.z); o[7] = f2bf(b.w);
    *(ushort8*)(xb + i) = o;
    return;
  }
  // ---- weight transposes: 11136 blocks ----
  const float* src; u16* dst; int R, Cc, Rpad, bx, by;
  if (z < 1536)       { src = w_dkv; dst = wcatT;              R = 2048; Cc = 672;  Rpad = 2048; int l = z;        bx = l % 64; by = l / 64; }
  else if (z < 3072)  { src = w_dq;  dst = wcatT + 768 * 2048; R = 2048; Cc = 672;  Rpad = 2048; int l = z - 1536; bx = l % 64; by = l / 64; }
  else if (z < 3200)  { src = w_kr;  dst = wcatT + 1536 * 2048;R = 2048; Cc = 64;   Rpad = 2048; int l = z - 3072; bx = l % 64; by = l / 64; }
  else if (z < 5504)  { src = w_ukv; dst = wukvT;              R = 672;  Cc = 3072; Rpad = 768;  int l = z - 3200; bx = l % 24; by = l / 24; }
  else if (z < 7040)  { src = w_q;   dst = wqT;                R = 672;  Cc = 2048; Rpad = 768;  int l = z - 5504; bx = l % 24; by = l / 24; }
  else                { src = w_cp;  dst = wcpT;               R = 2048; Cc = 2048; Rpad = 2048; int l = z - 7040; bx = l % 64; by = l / 64; }
  int tx = threadIdx.x & 31, ty = threadIdx.x >> 5;
  int r0 = bx * 32, c0 = by * 32;
#pragma unroll
  for (int i = 0; i < 4; i++) {
    int r = r0 + ty + 8 * i;
    int c = c0 + tx;
    sm[ty + 8 * i][tx] = (r < R && c < Cc) ? src[(size_t)r * Cc + c] : 0.f;
  }
  __syncthreads();
#pragma unroll
  for (int i = 0; i < 4; i++) {
    int c = c0 + ty + 8 * i;
    dst[(size_t)c * Rpad + r0 + tx] = f2bf(sm[tx][ty + 8 * i]);
  }
}

// ---------------- 128x128 GEMM, m97-style: linear LDS + global_load_lds w16, BK=32, strided ----------------
template <typename OT>
__global__ __launch_bounds__(256) void k_gemm128(const u16* __restrict__ A, int lda,
                                                 const u16* __restrict__ BT, int ldb,
                                                 OT* __restrict__ C, int ldc,
                                                 int K) {
  __shared__ __align__(16) u16 As[128 * 32];
  __shared__ __align__(16) u16 Bs[128 * 32];
  int t = threadIdx.x;
  int wid = t >> 6, lane = t & 63;
  int m0 = blockIdx.y * 128, n0 = blockIdx.x * 128;
  int c0 = wid * 2;
  int srow0 = c0 * 16 + (lane >> 2);
  int scol = (lane & 3) * 8;
  const u16* Ag0 = A + (size_t)(m0 + srow0) * lda + scol;
  const u16* Ag1 = A + (size_t)(m0 + srow0 + 16) * lda + scol;
  const u16* Bg0 = BT + (size_t)(n0 + srow0) * ldb + scol;
  const u16* Bg1 = BT + (size_t)(n0 + srow0 + 16) * ldb + scol;
  u16* Al0 = &As[c0 * 512];
  u16* Al1 = &As[c0 * 512 + 512];
  u16* Bl0 = &Bs[c0 * 512];
  u16* Bl1 = &Bs[c0 * 512 + 512];
  int wr = (wid >> 1) * 64, wc = (wid & 1) * 64;
  int fr = lane & 15, fo = (lane >> 4) * 8;
  f32x4 acc[4][4];
#pragma unroll
  for (int m = 0; m < 4; m++)
#pragma unroll
    for (int n = 0; n < 4; n++) acc[m][n] = (f32x4){0, 0, 0, 0};
  for (int k0 = 0; k0 < K; k0 += 32) {
    GLD16(Ag0 + k0, Al0);
    GLD16(Ag1 + k0, Al1);
    GLD16(Bg0 + k0, Bl0);
    GLD16(Bg1 + k0, Bl1);
    __syncthreads();
    bf16x8 af[4], bf[4];
#pragma unroll
    for (int m = 0; m < 4; m++) af[m] = *(const bf16x8*)&As[(wr + m * 16 + fr) * 32 + fo];
#pragma unroll
    for (int n = 0; n < 4; n++) bf[n] = *(const bf16x8*)&Bs[(wc + n * 16 + fr) * 32 + fo];
#pragma unroll
    for (int m = 0; m < 4; m++)
#pragma unroll
      for (int n = 0; n < 4; n++)
        acc[m][n] = __builtin_amdgcn_mfma_f32_16x16x32_bf16(af[m], bf[n], acc[m][n], 0, 0, 0);
    __syncthreads();
  }
  int cr = (lane >> 4) * 4, cc = lane & 15;
#pragma unroll
  for (int m = 0; m < 4; m++)
#pragma unroll
    for (int n = 0; n < 4; n++)
#pragma unroll
      for (int r = 0; r < 4; r++)
        st_out(&C[(size_t)(m0 + wr + m * 16 + cr + r) * ldc + n0 + wc + n * 16 + cc], acc[m][n][r]);
}

// ---------------- dual GEMM: blocks [0,24) -> kv; blocks [24,40) -> q with fused rope+rmsnorm -> qf ----------------
__global__ __launch_bounds__(256) void k_gemm_dual(const u16* __restrict__ catout,
                                                   const u16* __restrict__ wukvT,
                                                   u16* __restrict__ kvb,
                                                   const u16* __restrict__ wqT,
                                                   const float* __restrict__ cosp,
                                                   const float* __restrict__ sinp,
                                                   u16* __restrict__ qf) {
  __shared__ __align__(16) u16 As[128 * 32];
  __shared__ __align__(16) u16 Bs[128 * 32];
  int t = threadIdx.x;
  int wid = t >> 6, lane = t & 63;
  int bx = blockIdx.x;
  bool isq = (bx >= 24);
  int nx = isq ? bx - 24 : bx;
  int m0 = blockIdx.y * 128, n0 = nx * 128;
  const u16* A = isq ? catout + 768 : catout;
  const u16* BT = isq ? wqT : wukvT;
  int c0 = wid * 2;
  int srow0 = c0 * 16 + (lane >> 2);
  int scol = (lane & 3) * 8;
  const u16* Ag0 = A + (size_t)(m0 + srow0) * 1664 + scol;
  const u16* Ag1 = A + (size_t)(m0 + srow0 + 16) * 1664 + scol;
  const u16* Bg0 = BT + (size_t)(n0 + srow0) * 768 + scol;
  const u16* Bg1 = BT + (size_t)(n0 + srow0 + 16) * 768 + scol;
  u16* Al0 = &As[c0 * 512];
  u16* Al1 = &As[c0 * 512 + 512];
  u16* Bl0 = &Bs[c0 * 512];
  u16* Bl1 = &Bs[c0 * 512 + 512];
  int wr = (wid >> 1) * 64, wc = (wid & 1) * 64;
  int fr = lane & 15, fo = (lane >> 4) * 8;
  f32x4 acc[4][4];
#pragma unroll
  for (int m = 0; m < 4; m++)
#pragma unroll
    for (int n = 0; n < 4; n++) acc[m][n] = (f32x4){0, 0, 0, 0};
  for (int k0 = 0; k0 < 768; k0 += 32) {
    GLD16(Ag0 + k0, Al0);
    GLD16(Ag1 + k0, Al1);
    GLD16(Bg0 + k0, Bl0);
    GLD16(Bg1 + k0, Bl1);
    __syncthreads();
    bf16x8 af[4], bf[4];
#pragma unroll
    for (int m = 0; m < 4; m++) af[m] = *(const bf16x8*)&As[(wr + m * 16 + fr) * 32 + fo];
#pragma unroll
    for (int n = 0; n < 4; n++) bf[n] = *(const bf16x8*)&Bs[(wc + n * 16 + fr) * 32 + fo];
#pragma unroll
    for (int m = 0; m < 4; m++)
#pragma unroll
      for (int n = 0; n < 4; n++)
        acc[m][n] = __builtin_amdgcn_mfma_f32_16x16x32_bf16(af[m], bf[n], acc[m][n], 0, 0, 0);
    __syncthreads();
  }
  int cr = (lane >> 4) * 4, cc = lane & 15;
  if (!isq) {
#pragma unroll
    for (int m = 0; m < 4; m++)
#pragma unroll
      for (int n = 0; n < 4; n++)
#pragma unroll
        for (int r = 0; r < 4; r++)
          kvb[(size_t)(m0 + wr + m * 16 + cr + r) * 3072 + n0 + wc + n * 16 + cc] = f2bf(acc[m][n][r]);
    return;
  }
  int h = nx;
  int wch = wid & 1;
  int wrg = wid >> 1;
  if (wch == 1) {
#pragma unroll
    for (int m = 0; m < 4; m++)
#pragma unroll
      for (int r = 0; r < 4; r++) {
        int grow = m0 + wr + m * 16 + cr + r;
#pragma unroll
        for (int n = 0; n < 2; n++) {
          int i = n * 16 + cc;
          float cth = cosp[(size_t)grow * 32 + i];
          float sth = sinp[(size_t)grow * 32 + i];
          float x1 = acc[m][n][r], x2 = acc[m][n + 2][r];
          acc[m][n][r]     = x1 * cth + x2 * sth;
          acc[m][n + 2][r] = x2 * cth - x1 * sth;
        }
      }
  }
  float part[4][4];
#pragma unroll
  for (int m = 0; m < 4; m++)
#pragma unroll
    for (int r = 0; r < 4; r++) {
      float s2 = 0.f;
#pragma unroll
      for (int n = 0; n < 4; n++) s2 += acc[m][n][r] * acc[m][n][r];
#pragma unroll
      for (int o = 1; o < 16; o <<= 1) s2 += __shfl_xor(s2, o, 64);
      part[m][r] = s2;
    }
  float* xs = (float*)As;
  if (cc == 0) {
#pragma unroll
    for (int m = 0; m < 4; m++)
#pragma unroll
      for (int r = 0; r < 4; r++)
        xs[(wrg * 2 + wch) * 64 + m * 16 + cr + r] = part[m][r];
  }
  __syncthreads();
#pragma unroll
  for (int m = 0; m < 4; m++)
#pragma unroll
    for (int r = 0; r < 4; r++) {
      int lrow = m * 16 + cr + r;
      float tot = part[m][r] + xs[(wrg * 2 + (wch ^ 1)) * 64 + lrow];
      float rms = rsqrtf(tot * (1.f / 128.f) + 1.1920929e-7f) * 0.1275174245f;
      int grow = m0 + wr + lrow;
      int b2 = grow >> 11, tt = grow & 2047;
      size_t base = (((size_t)(b2 * NHEAD + h)) * TSEQ + tt) * 128 + wch * 64;
#pragma unroll
      for (int n = 0; n < 4; n++)
        qf[base + n * 16 + cc] = f2bf(acc[m][n][r] * rms);
    }
}

// ---------------- build K and V in one dispatch -> swizzled tile images [bh][tile][16KB] ----------------
__global__ __launch_bounds__(256) void k_build_kv(const u16* __restrict__ kv, const u16* __restrict__ kr,
                                                  const float* __restrict__ cosp, const float* __restrict__ sinp,
                                                  const float* __restrict__ ve, const float* __restrict__ gate,
                                                  u16* __restrict__ ksw, u16* __restrict__ vsw) {
  __shared__ __align__(16) char smraw[16384];
  int tid = threadIdx.x;
  if (blockIdx.x < 1024) {
    // ---- build K ----
    u16* sm = (u16*)smraw;
    int wid = tid >> 6, lane = tid & 63;
    int bh = blockIdx.x >> 5, tile = blockIdx.x & 31;
    int b = bh >> 4, h = bh & 15;
    int d0 = lane * 2;
    for (int rr = 0; rr < 16; rr++) {
      int row = wid * 16 + rr;
      int t = tile * 64 + row;
      int m = b * TSEQ + t;
      float v[2];
#pragma unroll
      for (int e = 0; e < 2; e++) {
        int d = d0 + e;
        float val;
        if (d < 64) {
          val = bf2f(kv[(size_t)m * 3072 + h * 192 + d]);
        } else {
          int dd = d - 64, i = dd & 31;
          float c = cosp[m * 32 + i], s = sinp[m * 32 + i];
          float x1 = bf2f(kr[(size_t)m * 1664 + i]), x2 = bf2f(kr[(size_t)m * 1664 + 32 + i]);
          val = (dd < 32) ? (x1 * c + x2 * s) : (x2 * c - x1 * s);
        }
        v[e] = val;
      }
      float ss = v[0] * v[0] + v[1] * v[1];
#pragma unroll
      for (int o = 1; o < 64; o <<= 1) ss += __shfl_xor(ss, o, 64);
      float rms = rsqrtf(ss * (1.f / 128.f) + 1.1920929e-7f);
      int a = (row * 256 + d0 * 2) ^ ((row & 7) << 4);
      sm[a >> 1] = f2bf(v[0] * rms);
      sm[(a >> 1) + 1] = f2bf(v[1] * rms);
    }
    __syncthreads();
    u16* dst = ksw + ((size_t)(bh * 32 + tile)) * 8192 + tid * 32;
    const u16* src = sm + tid * 32;
#pragma unroll
    for (int j = 0; j < 4; j++)
      *(ushort8*)(dst + j * 8) = *(const ushort8*)(src + j * 8);
  } else {
    // ---- build V ----
    char* sm = smraw;
    int bxv = blockIdx.x - 1024;
    int bh = bxv >> 5, tile = bxv & 31;
    int t0 = tile * 64;
    int b = bh >> 4, h = bh & 15;
    int tt = tid >> 2, dp = (tid & 3) * 32;
    int m = b * TSEQ + t0 + tt;
    float g = gate[m * 16 + h];
    const u16* kvp = kv + (size_t)m * 3072 + h * 192 + 64 + dp;
    const float* vep = ve + (size_t)m * 2048 + h * 128 + dp;
    ushort8 kvv[4];
    float4 vev[8];
#pragma unroll
    for (int u = 0; u < 4; u++) kvv[u] = *(const ushort8*)(kvp + u * 8);
#pragma unroll
    for (int u = 0; u < 8; u++) vev[u] = *(const float4*)(vep + u * 4);
#pragma unroll
    for (int j = 0; j < 32; j++) {
      float vvf = ((const float*)&vev[j >> 2])[j & 3];
      float v = bf2f(kvv[j >> 3][j & 7]) + g * vvf;
      int row = dp + j;
      int a = row * 128 + tt * 2;
      *(u16*)(sm + (a ^ ((row & 7) << 4))) = f2bf(v);
    }
    __syncthreads();
    u16* dst = vsw + ((size_t)(bh * 32 + tile)) * 8192 + tid * 32;
    const u16* src = (const u16*)sm + tid * 32;
#pragma unroll
    for (int j = 0; j < 4; j++)
      *(ushort8*)(dst + j * 8) = *(const ushort8*)(src + j * 8);
  }
}

// ---------------- flash attention v2 (round-12/14): 128-row blocks, 32 q-rows/wave, staged K/V, balanced qb ----------------
__global__ __launch_bounds__(256, 2) void k_attn(const u16* __restrict__ qf, const u16* __restrict__ ksw,
                                                 const u16* __restrict__ vsw, u16* __restrict__ y) {
  __shared__ __align__(16) u16 kvbuf[2][2][8192]; // [buf][K=0/V=1][16KB]
  __shared__ __align__(16) char plds_all[4][4096]; // per wave: P [32 q][64 k] bf16, XOR-swizzled
  int tid = threadIdx.x, wid = tid >> 6, lane = tid & 63;
  int gq = lane >> 4, c = lane & 15;
  int task = (blockIdx.x & 7) * 64 + (blockIdx.x >> 3); // 512 blocks, XCD-chunked
  int bh = task >> 4;
  int tq = task & 15;
  int qb = ((task >> 5) & 1) ? tq : 15 - tq; // complementary pairing: blocks i,i+256 -> qb x,15-x (same CU)
  int nt = 2 * qb + 2;
  int q0w = qb * 128 + wid * 32;        // this wave's 32-row base
  const u16* qp = qf + (size_t)bh * TSEQ * 128;
  const u16* kswb = ksw + (size_t)bh * 32 * 8192;
  const u16* vswb = vsw + (size_t)bh * 32 * 8192;
  char* plds = plds_all[wid];
  int swz = (c & 7) << 4;
  bf16x8 qfr[2][4];
#pragma unroll
  for (int rg = 0; rg < 2; rg++)
#pragma unroll
    for (int kc = 0; kc < 4; kc++)
      qfr[rg][kc] = *(const bf16x8*)(qp + (size_t)(q0w + rg * 16 + c) * 128 + kc * 32 + gq * 8);
  f32x4 oacc[2][8];
#pragma unroll
  for (int rg = 0; rg < 2; rg++)
#pragma unroll
    for (int nd = 0; nd < 8; nd++) oacc[rg][nd] = (f32x4){0, 0, 0, 0};
  float mreg[2] = {-1e30f, -1e30f}, lreg[2] = {0.f, 0.f};
  int chunk = wid * 4;
#pragma unroll
  for (int j = 0; j < 4; j++) {
    GLD16(kswb + (chunk + j) * 512 + lane * 8, &kvbuf[0][0][(chunk + j) * 512]);
    GLD16(vswb + (chunk + j) * 512 + lane * 8, &kvbuf[0][1][(chunk + j) * 512]);
  }
  __syncthreads();
  for (int it = 0; it < nt; it++) {
    int cur = it & 1;
    if (it + 1 < nt) {
      const u16* kt = kswb + (size_t)(it + 1) * 8192;
      const u16* vt = vswb + (size_t)(it + 1) * 8192;
#pragma unroll
      for (int j = 0; j < 4; j++) {
        GLD16(kt + (chunk + j) * 512 + lane * 8, &kvbuf[cur ^ 1][0][(chunk + j) * 512]);
        GLD16(vt + (chunk + j) * 512 + lane * 8, &kvbuf[cur ^ 1][1][(chunk + j) * 512]);
      }
    }
    int kt0 = it * 64;
    if (kt0 <= q0w + 31) { // wave-uniform skip of fully-masked tiles
      const char* Kt = (const char*)kvbuf[cur][0];
      const char* Vt = (const char*)kvbuf[cur][1];
      bool maskit = (kt0 + 63 > q0w);
      f32x4 sacc[2][4];
#pragma unroll
      for (int rg = 0; rg < 2; rg++)
#pragma unroll
        for (int s = 0; s < 4; s++) sacc[rg][s] = (f32x4){0, 0, 0, 0};
#pragma unroll
      for (int s = 0; s < 4; s++) {
        int row = s * 16 + c;
#pragma unroll
        for (int kc = 0; kc < 4; kc++) {
          int a = (row * 256 + (kc * 32 + gq * 8) * 2) ^ ((row & 7) << 4);
          bf16x8 kfr = *(const bf16x8*)(Kt + a);
          sacc[0][s] = __builtin_amdgcn_mfma_f32_16x16x32_bf16(kfr, qfr[0][kc], sacc[0][s], 0, 0, 0);
          sacc[1][s] = __builtin_amdgcn_mfma_f32_16x16x32_bf16(kfr, qfr[1][kc], sacc[1][s], 0, 0, 0);
        }
      }
      if (maskit) {
#pragma unroll
        for (int rg = 0; rg < 2; rg++) {
          int qrow = q0w + rg * 16 + c;
#pragma unroll
          for (int s = 0; s < 4; s++)
#pragma unroll
            for (int r = 0; r < 4; r++) {
              int key = kt0 + s * 16 + gq * 4 + r;
              sacc[rg][s][r] = (key <= qrow) ? sacc[rg][s][r] : -3e38f;
            }
        }
      }
      float mx[2];
#pragma unroll
      for (int rg = 0; rg < 2; rg++) {
        float m2 = sacc[rg][0][0];
#pragma unroll
        for (int s = 0; s < 4; s++)
#pragma unroll
          for (int r = 0; r < 4; r++) m2 = fmaxf(m2, sacc[rg][s][r]);
        m2 = fmaxf(m2, __shfl_xor(m2, 16, 64));
        m2 = fmaxf(m2, __shfl_xor(m2, 32, 64));
        mx[rg] = m2;
      }
      bool ok = (mx[0] - mreg[0] <= 11.f) && (mx[1] - mreg[1] <= 11.f);
      if (!__all(ok)) {
#pragma unroll
        for (int rg = 0; rg < 2; rg++) {
          float mn = fmaxf(mreg[rg], mx[rg]);
          float fac = exp2f(mreg[rg] - mn);
          lreg[rg] *= fac;
          float fq[4];
#pragma unroll
          for (int r = 0; r < 4; r++) fq[r] = __shfl(fac, gq * 4 + r, 64);
#pragma unroll
          for (int nd = 0; nd < 8; nd++)
#pragma unroll
            for (int r = 0; r < 4; r++) oacc[rg][nd][r] *= fq[r];
          mreg[rg] = mn;
        }
      }
#pragma unroll
      for (int rg = 0; rg < 2; rg++) {
        float p[4][4];
        float rs = 0.f;
#pragma unroll
        for (int s = 0; s < 4; s++)
#pragma unroll
          for (int r = 0; r < 4; r++) {
            p[s][r] = exp2f(sacc[rg][s][r] - mreg[rg]);
            rs += p[s][r];
          }
        rs += __shfl_xor(rs, 16, 64);
        rs += __shfl_xor(rs, 32, 64);
        lreg[rg] += rs;
#pragma unroll
        for (int s = 0; s < 4; s++) {
          u32 w0 = cvtpk(p[s][0], p[s][1]);
          u32 w1 = cvtpk(p[s][2], p[s][3]);
          int a = (rg * 2048 + c * 128 + s * 32 + gq * 8) ^ swz;
          *(uint2*)(plds + a) = make_uint2(w0, w1);
        }
      }
#pragma unroll
      for (int kc2 = 0; kc2 < 2; kc2++) {
        int a0 = (c * 128 + kc2 * 64 + gq * 16) ^ swz;
        bf16x8 pa0 = *(const bf16x8*)(plds + a0);
        bf16x8 pa1 = *(const bf16x8*)(plds + 2048 + a0);
#pragma unroll
        for (int nd = 0; nd < 8; nd++) {
          int vrow = nd * 16 + c;
          int av = (vrow * 128 + (kc2 * 32 + gq * 8) * 2) ^ ((vrow & 7) << 4);
          bf16x8 vfr = *(const bf16x8*)(Vt + av);
          oacc[0][nd] = __builtin_amdgcn_mfma_f32_16x16x32_bf16(pa0, vfr, oacc[0][nd], 0, 0, 0);
          oacc[1][nd] = __builtin_amdgcn_mfma_f32_16x16x32_bf16(pa1, vfr, oacc[1][nd], 0, 0, 0);
        }
      }
    }
    __syncthreads();
  }
  int b2 = bh >> 4, h2 = bh & 15;
#pragma unroll
  for (int rg = 0; rg < 2; rg++) {
    float linv = 1.f / lreg[rg];
    float inv[4];
#pragma unroll
    for (int r = 0; r < 4; r++) inv[r] = __shfl(linv, gq * 4 + r, 64);
#pragma unroll
    for (int nd = 0; nd < 8; nd++) {
#pragma unroll
      for (int r = 0; r < 4; r++) {
        size_t offo = ((size_t)(b2 * TSEQ + q0w + rg * 16 + gq * 4 + r)) * 2048 + h2 * 128 + nd * 16 + c;
        y[offo] = f2bf(oacc[rg][nd][r] * inv[r]);
      }
    }
  }
}

extern "C" void kernel_launch(void* const* d_in, const int* in_sizes, int n_in,
                              void* d_out, int out_size, void* d_ws, size_t ws_size,
                              hipStream_t stream) {
  (void)in_sizes; (void)n_in; (void)out_size; (void)ws_size;
  const float* x      = (const float*)d_in[0];
  const float* ve     = (const float*)d_in[1];
  const float* cosp   = (const float*)d_in[2];
  const float* sinp   = (const float*)d_in[3];
  const float* w_dkv  = (const float*)d_in[4];
  const float* w_ukv  = (const float*)d_in[5];
  const float* w_kr   = (const float*)d_in[6];
  const float* w_dq   = (const float*)d_in[7];
  const float* w_q    = (const float*)d_in[8];
  const float* w_cp   = (const float*)d_in[9];
  const float* w_vg   = (const float*)d_in[10];
  float* out = (float*)d_out;   // reference output dtype is float32

  char* ws = (char*)d_ws;
  size_t off = 0;
  auto alloc = [&](size_t bytes) -> char* {
    char* p = ws + off;
    off += (bytes + 255) & ~(size_t)255;
    return p;
  };
  u16* xb     = (u16*)alloc(4096ull * 2048 * 2);
  u16* wcatT  = (u16*)alloc(1664ull * 2048 * 2);  // rows: [0,768)=dkv, [768,1536)=dq, [1536,1600)=kr
  u16* wukvT  = (u16*)alloc(3072ull * 768 * 2);
  u16* wqT    = (u16*)alloc(2048ull * 768 * 2);
  u16* wcpT   = (u16*)alloc(2048ull * 2048 * 2);
  u16* catout = (u16*)alloc(4096ull * 1664 * 2);  // cols: [0,768)=ckv, [768,1536)=q1, [1536,1600)=kr
  u16* kvb    = (u16*)alloc(4096ull * 3072 * 2);
  float* gateb = (float*)alloc(4096ull * 16 * 4);
  u16* qfb    = (u16*)alloc(2ull * 16 * 2048 * 128 * 2);
  u16* kswb   = (u16*)alloc(32ull * 32 * 8192 * 2);
  u16* vswb   = (u16*)alloc(32ull * 32 * 8192 * 2);
  u16* yb = xb; // alias: x_bf dead after the cat GEMM

  // 1. prep: all transposes + x->bf16 + gate in ONE dispatch
  k_prep<<<dim3(15488), dim3(256), 0, stream>>>(x, w_dkv, w_dq, w_kr, w_ukv, w_q, w_cp, w_vg,
                                                xb, wcatT, wukvT, wqT, wcpT, gateb);

  // 2. projection GEMMs: cat (x-projections), then fused {ukv | q+build_q}
  k_gemm128<u16><<<dim3(13, 32), dim3(256), 0, stream>>>(xb, 2048, wcatT, 2048, catout, 1664, 2048);
  k_gemm_dual<<<dim3(40, 32), dim3(256), 0, stream>>>(catout, wukvT, kvb, wqT, cosp, sinp, qfb);

  // 3. build k + v in ONE dispatch (emit pre-swizzled 16KB tile images)
  k_build_kv<<<dim3(2048), dim3(256), 0, stream>>>(kvb, catout + 1536, cosp, sinp, ve, gateb, kswb, vswb);

  // 4. attention -> y (aliases xb): 512 blocks x 4 waves x 32 rows/wave, CU-balanced
  k_attn<<<dim3(512), dim3(256), 0, stream>>>(qfb, kswb, vswb, yb);

  // 5. output projection (f32 out -> d_out)
  k_gemm128<float><<<dim3(16, 32), dim3(256), 0, stream>>>(yb, 2048, wcpT, 2048, out, 2048, 2048);
}

// Round 19
// 294.721 us; speedup vs baseline: 1.7971x; 1.0762x over previous
//
#include <hip/hip_runtime.h>
#include <hip/hip_bf16.h>

typedef unsigned short u16;
typedef unsigned int u32;
typedef __bf16 bf16x8 __attribute__((ext_vector_type(8)));
typedef float f32x4 __attribute__((ext_vector_type(4)));
typedef u16 ushort8 __attribute__((ext_vector_type(8)));

#define TSEQ 2048
#define NHEAD 16

#define GLD16(gp, lp) __builtin_amdgcn_global_load_lds( \
    (__attribute__((address_space(1))) void*)(gp), \
    (__attribute__((address_space(3))) void*)(lp), 16, 0, 0)

static __device__ __forceinline__ float bf2f(u16 u) {
  unsigned int x = ((unsigned int)u) << 16;
  union { unsigned int i; float f; } c; c.i = x; return c.f;
}
static __device__ __forceinline__ u16 f2bf(float f) {
  union { float f; unsigned int i; } c; c.f = f;
  unsigned int x = c.i;
  unsigned int r = (x + 0x7FFFu + ((x >> 16) & 1u)) >> 16;
  return (u16)r;
}
static __device__ __forceinline__ void st_out(u16* p, float v) { *p = f2bf(v); }
static __device__ __forceinline__ void st_out(float* p, float v) { *p = v; }
static __device__ __forceinline__ u32 cvtpk(float lo, float hi) {
  u32 w;
  asm("v_cvt_pk_bf16_f32 %0, %1, %2" : "=v"(w) : "v"(lo), "v"(hi));
  return w;
}

// -------- PREP: all weight transposes + x conversion + gate in ONE dispatch (block-range switch) --------
__global__ __launch_bounds__(256) void k_prep(const float* __restrict__ x,
                                              const float* __restrict__ w_dkv, const float* __restrict__ w_dq,
                                              const float* __restrict__ w_kr, const float* __restrict__ w_ukv,
                                              const float* __restrict__ w_q, const float* __restrict__ w_cp,
                                              const float* __restrict__ w_vg,
                                              u16* __restrict__ xb,
                                              u16* __restrict__ wcatT, u16* __restrict__ wukvT,
                                              u16* __restrict__ wqT, u16* __restrict__ wcpT,
                                              float* __restrict__ gateb) {
  __shared__ float sm[32][33];
  int z = blockIdx.x;
  if (z >= 15232) { // ---- gate: 256 blocks ----
    int idx = (z - 15232) * 256 + threadIdx.x; // m*16 + h
    int m = idx >> 4, h = idx & 15;
    const float* xr = x + (size_t)m * 2048;
    float s = 0.f;
#pragma unroll
    for (int j = 0; j < 32; j++) s += xr[j] * w_vg[j * 16 + h];
    gateb[idx] = 2.f / (1.f + __expf(-s));
    return;
  }
  if (z >= 11136) { // ---- conv_x: 4096 blocks ----
    size_t i = ((size_t)(z - 11136) * 256 + threadIdx.x) * 8;
    float4 a = *(const float4*)(x + i);
    float4 b = *(const float4*)(x + i + 4);
    ushort8 o;
    o[0] = f2bf(a.x); o[1] = f2bf(a.y); o[2] = f2bf(a.z); o[3] = f2bf(a.w);
    o[4] = f2bf(b.x); o[5] = f2bf(b.y); o[6] = f2bf(b.z); o[7] = f2bf(b.w);
    *(ushort8*)(xb + i) = o;
    return;
  }
  // ---- weight transposes: 11136 blocks ----
  const float* src; u16* dst; int R, Cc, Rpad, bx, by;
  if (z < 1536)       { src = w_dkv; dst = wcatT;              R = 2048; Cc = 672;  Rpad = 2048; int l = z;        bx = l % 64; by = l / 64; }
  else if (z < 3072)  { src = w_dq;  dst = wcatT + 768 * 2048; R = 2048; Cc = 672;  Rpad = 2048; int l = z - 1536; bx = l % 64; by = l / 64; }
  else if (z < 3200)  { src = w_kr;  dst = wcatT + 1536 * 2048;R = 2048; Cc = 64;   Rpad = 2048; int l = z - 3072; bx = l % 64; by = l / 64; }
  else if (z < 5504)  { src = w_ukv; dst = wukvT;              R = 672;  Cc = 3072; Rpad = 768;  int l = z - 3200; bx = l % 24; by = l / 24; }
  else if (z < 7040)  { src = w_q;   dst = wqT;                R = 672;  Cc = 2048; Rpad = 768;  int l = z - 5504; bx = l % 24; by = l / 24; }
  else                { src = w_cp;  dst = wcpT;               R = 2048; Cc = 2048; Rpad = 2048; int l = z - 7040; bx = l % 64; by = l / 64; }
  int tx = threadIdx.x & 31, ty = threadIdx.x >> 5;
  int r0 = bx * 32, c0 = by * 32;
#pragma unroll
  for (int i = 0; i < 4; i++) {
    int r = r0 + ty + 8 * i;
    int c = c0 + tx;
    sm[ty + 8 * i][tx] = (r < R && c < Cc) ? src[(size_t)r * Cc + c] : 0.f;
  }
  __syncthreads();
#pragma unroll
  for (int i = 0; i < 4; i++) {
    int c = c0 + ty + 8 * i;
    dst[(size_t)c * Rpad + r0 + tx] = f2bf(sm[tx][ty + 8 * i]);
  }
}

// ---- 128x128 GEMM, BK=64 via two 32-col LDS panels (halved barrier count), global_load_lds w16 ----
template <typename OT>
__global__ __launch_bounds__(256) void k_gemm128(const u16* __restrict__ A, int lda,
                                                 const u16* __restrict__ BT, int ldb,
                                                 OT* __restrict__ C, int ldc,
                                                 int K) {
  __shared__ __align__(16) u16 As[2][128 * 32];
  __shared__ __align__(16) u16 Bs[2][128 * 32];
  int t = threadIdx.x;
  int wid = t >> 6, lane = t & 63;
  int m0 = blockIdx.y * 128, n0 = blockIdx.x * 128;
  int c0 = wid * 2;
  int srow0 = c0 * 16 + (lane >> 2);
  int scol = (lane & 3) * 8;
  const u16* Ag0 = A + (size_t)(m0 + srow0) * lda + scol;
  const u16* Ag1 = A + (size_t)(m0 + srow0 + 16) * lda + scol;
  const u16* Bg0 = BT + (size_t)(n0 + srow0) * ldb + scol;
  const u16* Bg1 = BT + (size_t)(n0 + srow0 + 16) * ldb + scol;
  int wr = (wid >> 1) * 64, wc = (wid & 1) * 64;
  int fr = lane & 15, fo = (lane >> 4) * 8;
  f32x4 acc[4][4];
#pragma unroll
  for (int m = 0; m < 4; m++)
#pragma unroll
    for (int n = 0; n < 4; n++) acc[m][n] = (f32x4){0, 0, 0, 0};
  for (int k0 = 0; k0 < K; k0 += 64) {
#pragma unroll
    for (int p = 0; p < 2; p++) {
      GLD16(Ag0 + k0 + p * 32, &As[p][c0 * 512]);
      GLD16(Ag1 + k0 + p * 32, &As[p][c0 * 512 + 512]);
      GLD16(Bg0 + k0 + p * 32, &Bs[p][c0 * 512]);
      GLD16(Bg1 + k0 + p * 32, &Bs[p][c0 * 512 + 512]);
    }
    __syncthreads();
#pragma unroll
    for (int p = 0; p < 2; p++) {
      bf16x8 af[4], bf[4];
#pragma unroll
      for (int m = 0; m < 4; m++) af[m] = *(const bf16x8*)&As[p][(wr + m * 16 + fr) * 32 + fo];
#pragma unroll
      for (int n = 0; n < 4; n++) bf[n] = *(const bf16x8*)&Bs[p][(wc + n * 16 + fr) * 32 + fo];
#pragma unroll
      for (int m = 0; m < 4; m++)
#pragma unroll
        for (int n = 0; n < 4; n++)
          acc[m][n] = __builtin_amdgcn_mfma_f32_16x16x32_bf16(af[m], bf[n], acc[m][n], 0, 0, 0);
    }
    __syncthreads();
  }
  int cr = (lane >> 4) * 4, cc = lane & 15;
#pragma unroll
  for (int m = 0; m < 4; m++)
#pragma unroll
    for (int n = 0; n < 4; n++)
#pragma unroll
      for (int r = 0; r < 4; r++)
        st_out(&C[(size_t)(m0 + wr + m * 16 + cr + r) * ldc + n0 + wc + n * 16 + cc], acc[m][n][r]);
}

// ---------------- dual GEMM (BK=64 panels): blocks [0,24) -> kv; [24,40) -> q + fused rope/rmsnorm ----------------
__global__ __launch_bounds__(256) void k_gemm_dual(const u16* __restrict__ catout,
                                                   const u16* __restrict__ wukvT,
                                                   u16* __restrict__ kvb,
                                                   const u16* __restrict__ wqT,
                                                   const float* __restrict__ cosp,
                                                   const float* __restrict__ sinp,
                                                   u16* __restrict__ qf) {
  __shared__ __align__(16) u16 As[2][128 * 32];
  __shared__ __align__(16) u16 Bs[2][128 * 32];
  int t = threadIdx.x;
  int wid = t >> 6, lane = t & 63;
  int bx = blockIdx.x;
  bool isq = (bx >= 24);
  int nx = isq ? bx - 24 : bx;
  int m0 = blockIdx.y * 128, n0 = nx * 128;
  const u16* A = isq ? catout + 768 : catout;
  const u16* BT = isq ? wqT : wukvT;
  int c0 = wid * 2;
  int srow0 = c0 * 16 + (lane >> 2);
  int scol = (lane & 3) * 8;
  const u16* Ag0 = A + (size_t)(m0 + srow0) * 1664 + scol;
  const u16* Ag1 = A + (size_t)(m0 + srow0 + 16) * 1664 + scol;
  const u16* Bg0 = BT + (size_t)(n0 + srow0) * 768 + scol;
  const u16* Bg1 = BT + (size_t)(n0 + srow0 + 16) * 768 + scol;
  int wr = (wid >> 1) * 64, wc = (wid & 1) * 64;
  int fr = lane & 15, fo = (lane >> 4) * 8;
  f32x4 acc[4][4];
#pragma unroll
  for (int m = 0; m < 4; m++)
#pragma unroll
    for (int n = 0; n < 4; n++) acc[m][n] = (f32x4){0, 0, 0, 0};
  for (int k0 = 0; k0 < 768; k0 += 64) {
#pragma unroll
    for (int p = 0; p < 2; p++) {
      GLD16(Ag0 + k0 + p * 32, &As[p][c0 * 512]);
      GLD16(Ag1 + k0 + p * 32, &As[p][c0 * 512 + 512]);
      GLD16(Bg0 + k0 + p * 32, &Bs[p][c0 * 512]);
      GLD16(Bg1 + k0 + p * 32, &Bs[p][c0 * 512 + 512]);
    }
    __syncthreads();
#pragma unroll
    for (int p = 0; p < 2; p++) {
      bf16x8 af[4], bf[4];
#pragma unroll
      for (int m = 0; m < 4; m++) af[m] = *(const bf16x8*)&As[p][(wr + m * 16 + fr) * 32 + fo];
#pragma unroll
      for (int n = 0; n < 4; n++) bf[n] = *(const bf16x8*)&Bs[p][(wc + n * 16 + fr) * 32 + fo];
#pragma unroll
      for (int m = 0; m < 4; m++)
#pragma unroll
        for (int n = 0; n < 4; n++)
          acc[m][n] = __builtin_amdgcn_mfma_f32_16x16x32_bf16(af[m], bf[n], acc[m][n], 0, 0, 0);
    }
    __syncthreads();
  }
  int cr = (lane >> 4) * 4, cc = lane & 15;
  if (!isq) {
#pragma unroll
    for (int m = 0; m < 4; m++)
#pragma unroll
      for (int n = 0; n < 4; n++)
#pragma unroll
        for (int r = 0; r < 4; r++)
          kvb[(size_t)(m0 + wr + m * 16 + cr + r) * 3072 + n0 + wc + n * 16 + cc] = f2bf(acc[m][n][r]);
    return;
  }
  int h = nx;
  int wch = wid & 1;
  int wrg = wid >> 1;
  if (wch == 1) {
#pragma unroll
    for (int m = 0; m < 4; m++)
#pragma unroll
      for (int r = 0; r < 4; r++) {
        int grow = m0 + wr + m * 16 + cr + r;
#pragma unroll
        for (int n = 0; n < 2; n++) {
          int i = n * 16 + cc;
          float cth = cosp[(size_t)grow * 32 + i];
          float sth = sinp[(size_t)grow * 32 + i];
          float x1 = acc[m][n][r], x2 = acc[m][n + 2][r];
          acc[m][n][r]     = x1 * cth + x2 * sth;
          acc[m][n + 2][r] = x2 * cth - x1 * sth;
        }
      }
  }
  float part[4][4];
#pragma unroll
  for (int m = 0; m < 4; m++)
#pragma unroll
    for (int r = 0; r < 4; r++) {
      float s2 = 0.f;
#pragma unroll
      for (int n = 0; n < 4; n++) s2 += acc[m][n][r] * acc[m][n][r];
#pragma unroll
      for (int o = 1; o < 16; o <<= 1) s2 += __shfl_xor(s2, o, 64);
      part[m][r] = s2;
    }
  float* xs = (float*)&As[0][0];
  if (cc == 0) {
#pragma unroll
    for (int m = 0; m < 4; m++)
#pragma unroll
      for (int r = 0; r < 4; r++)
        xs[(wrg * 2 + wch) * 64 + m * 16 + cr + r] = part[m][r];
  }
  __syncthreads();
#pragma unroll
  for (int m = 0; m < 4; m++)
#pragma unroll
    for (int r = 0; r < 4; r++) {
      int lrow = m * 16 + cr + r;
      float tot = part[m][r] + xs[(wrg * 2 + (wch ^ 1)) * 64 + lrow];
      float rms = rsqrtf(tot * (1.f / 128.f) + 1.1920929e-7f) * 0.1275174245f;
      int grow = m0 + wr + lrow;
      int b2 = grow >> 11, tt = grow & 2047;
      size_t base = (((size_t)(b2 * NHEAD + h)) * TSEQ + tt) * 128 + wch * 64;
#pragma unroll
      for (int n = 0; n < 4; n++)
        qf[base + n * 16 + cc] = f2bf(acc[m][n][r] * rms);
    }
}

// ---------------- build K and V in one dispatch -> swizzled tile images [bh][tile][16KB] ----------------
__global__ __launch_bounds__(256) void k_build_kv(const u16* __restrict__ kv, const u16* __restrict__ kr,
                                                  const float* __restrict__ cosp, const float* __restrict__ sinp,
                                                  const float* __restrict__ ve, const float* __restrict__ gate,
                                                  u16* __restrict__ ksw, u16* __restrict__ vsw) {
  __shared__ __align__(16) char smraw[16384];
  int tid = threadIdx.x;
  if (blockIdx.x < 1024) {
    // ---- build K ----
    u16* sm = (u16*)smraw;
    int wid = tid >> 6, lane = tid & 63;
    int bh = blockIdx.x >> 5, tile = blockIdx.x & 31;
    int b = bh >> 4, h = bh & 15;
    int d0 = lane * 2;
    for (int rr = 0; rr < 16; rr++) {
      int row = wid * 16 + rr;
      int t = tile * 64 + row;
      int m = b * TSEQ + t;
      float v[2];
#pragma unroll
      for (int e = 0; e < 2; e++) {
        int d = d0 + e;
        float val;
        if (d < 64) {
          val = bf2f(kv[(size_t)m * 3072 + h * 192 + d]);
        } else {
          int dd = d - 64, i = dd & 31;
          float c = cosp[m * 32 + i], s = sinp[m * 32 + i];
          float x1 = bf2f(kr[(size_t)m * 1664 + i]), x2 = bf2f(kr[(size_t)m * 1664 + 32 + i]);
          val = (dd < 32) ? (x1 * c + x2 * s) : (x2 * c - x1 * s);
        }
        v[e] = val;
      }
      float ss = v[0] * v[0] + v[1] * v[1];
#pragma unroll
      for (int o = 1; o < 64; o <<= 1) ss += __shfl_xor(ss, o, 64);
      float rms = rsqrtf(ss * (1.f / 128.f) + 1.1920929e-7f);
      int a = (row * 256 + d0 * 2) ^ ((row & 7) << 4);
      sm[a >> 1] = f2bf(v[0] * rms);
      sm[(a >> 1) + 1] = f2bf(v[1] * rms);
    }
    __syncthreads();
    u16* dst = ksw + ((size_t)(bh * 32 + tile)) * 8192 + tid * 32;
    const u16* src = sm + tid * 32;
#pragma unroll
    for (int j = 0; j < 4; j++)
      *(ushort8*)(dst + j * 8) = *(const ushort8*)(src + j * 8);
  } else {
    // ---- build V ----
    char* sm = smraw;
    int bxv = blockIdx.x - 1024;
    int bh = bxv >> 5, tile = bxv & 31;
    int t0 = tile * 64;
    int b = bh >> 4, h = bh & 15;
    int tt = tid >> 2, dp = (tid & 3) * 32;
    int m = b * TSEQ + t0 + tt;
    float g = gate[m * 16 + h];
    const u16* kvp = kv + (size_t)m * 3072 + h * 192 + 64 + dp;
    const float* vep = ve + (size_t)m * 2048 + h * 128 + dp;
    ushort8 kvv[4];
    float4 vev[8];
#pragma unroll
    for (int u = 0; u < 4; u++) kvv[u] = *(const ushort8*)(kvp + u * 8);
#pragma unroll
    for (int u = 0; u < 8; u++) vev[u] = *(const float4*)(vep + u * 4);
#pragma unroll
    for (int j = 0; j < 32; j++) {
      float vvf = ((const float*)&vev[j >> 2])[j & 3];
      float v = bf2f(kvv[j >> 3][j & 7]) + g * vvf;
      int row = dp + j;
      int a = row * 128 + tt * 2;
      *(u16*)(sm + (a ^ ((row & 7) << 4))) = f2bf(v);
    }
    __syncthreads();
    u16* dst = vsw + ((size_t)(bh * 32 + tile)) * 8192 + tid * 32;
    const u16* src = (const u16*)sm + tid * 32;
#pragma unroll
    for (int j = 0; j < 4; j++)
      *(ushort8*)(dst + j * 8) = *(const ushort8*)(src + j * 8);
  }
}

// ---------------- flash attention v2: 128-row blocks, 32 q-rows/wave, staged K/V, balanced qb ----------------
__global__ __launch_bounds__(256, 2) void k_attn(const u16* __restrict__ qf, const u16* __restrict__ ksw,
                                                 const u16* __restrict__ vsw, u16* __restrict__ y) {
  __shared__ __align__(16) u16 kvbuf[2][2][8192]; // [buf][K=0/V=1][16KB]
  __shared__ __align__(16) char plds_all[4][4096]; // per wave: P [32 q][64 k] bf16, XOR-swizzled
  int tid = threadIdx.x, wid = tid >> 6, lane = tid & 63;
  int gq = lane >> 4, c = lane & 15;
  int task = (blockIdx.x & 7) * 64 + (blockIdx.x >> 3); // 512 blocks, XCD-chunked
  int bh = task >> 4;
  int tq = task & 15;
  int qb = ((task >> 5) & 1) ? tq : 15 - tq; // complementary pairing: blocks i,i+256 -> qb x,15-x (same CU)
  int nt = 2 * qb + 2;
  int q0w = qb * 128 + wid * 32;        // this wave's 32-row base
  const u16* qp = qf + (size_t)bh * TSEQ * 128;
  const u16* kswb = ksw + (size_t)bh * 32 * 8192;
  const u16* vswb = vsw + (size_t)bh * 32 * 8192;
  char* plds = plds_all[wid];
  int swz = (c & 7) << 4;
  bf16x8 qfr[2][4];
#pragma unroll
  for (int rg = 0; rg < 2; rg++)
#pragma unroll
    for (int kc = 0; kc < 4; kc++)
      qfr[rg][kc] = *(const bf16x8*)(qp + (size_t)(q0w + rg * 16 + c) * 128 + kc * 32 + gq * 8);
  f32x4 oacc[2][8];
#pragma unroll
  for (int rg = 0; rg < 2; rg++)
#pragma unroll
    for (int nd = 0; nd < 8; nd++) oacc[rg][nd] = (f32x4){0, 0, 0, 0};
  float mreg[2] = {-1e30f, -1e30f}, lreg[2] = {0.f, 0.f};
  int chunk = wid * 4;
#pragma unroll
  for (int j = 0; j < 4; j++) {
    GLD16(kswb + (chunk + j) * 512 + lane * 8, &kvbuf[0][0][(chunk + j) * 512]);
    GLD16(vswb + (chunk + j) * 512 + lane * 8, &kvbuf[0][1][(chunk + j) * 512]);
  }
  __syncthreads();
  for (int it = 0; it < nt; it++) {
    int cur = it & 1;
    if (it + 1 < nt) {
      const u16* kt = kswb + (size_t)(it + 1) * 8192;
      const u16* vt = vswb + (size_t)(it + 1) * 8192;
#pragma unroll
      for (int j = 0; j < 4; j++) {
        GLD16(kt + (chunk + j) * 512 + lane * 8, &kvbuf[cur ^ 1][0][(chunk + j) * 512]);
        GLD16(vt + (chunk + j) * 512 + lane * 8, &kvbuf[cur ^ 1][1][(chunk + j) * 512]);
      }
    }
    int kt0 = it * 64;
    if (kt0 <= q0w + 31) { // wave-uniform skip of fully-masked tiles
      const char* Kt = (const char*)kvbuf[cur][0];
      const char* Vt = (const char*)kvbuf[cur][1];
      bool maskit = (kt0 + 63 > q0w);
      f32x4 sacc[2][4];
#pragma unroll
      for (int rg = 0; rg < 2; rg++)
#pragma unroll
        for (int s = 0; s < 4; s++) sacc[rg][s] = (f32x4){0, 0, 0, 0};
#pragma unroll
      for (int s = 0; s < 4; s++) {
        int row = s * 16 + c;
#pragma unroll
        for (int kc = 0; kc < 4; kc++) {
          int a = (row * 256 + (kc * 32 + gq * 8) * 2) ^ ((row & 7) << 4);
          bf16x8 kfr = *(const bf16x8*)(Kt + a);
          sacc[0][s] = __builtin_amdgcn_mfma_f32_16x16x32_bf16(kfr, qfr[0][kc], sacc[0][s], 0, 0, 0);
          sacc[1][s] = __builtin_amdgcn_mfma_f32_16x16x32_bf16(kfr, qfr[1][kc], sacc[1][s], 0, 0, 0);
        }
      }
      if (maskit) {
#pragma unroll
        for (int rg = 0; rg < 2; rg++) {
          int qrow = q0w + rg * 16 + c;
#pragma unroll
          for (int s = 0; s < 4; s++)
#pragma unroll
            for (int r = 0; r < 4; r++) {
              int key = kt0 + s * 16 + gq * 4 + r;
              sacc[rg][s][r] = (key <= qrow) ? sacc[rg][s][r] : -3e38f;
            }
        }
      }
      float mx[2];
#pragma unroll
      for (int rg = 0; rg < 2; rg++) {
        float m2 = sacc[rg][0][0];
#pragma unroll
        for (int s = 0; s < 4; s++)
#pragma unroll
          for (int r = 0; r < 4; r++) m2 = fmaxf(m2, sacc[rg][s][r]);
        m2 = fmaxf(m2, __shfl_xor(m2, 16, 64));
        m2 = fmaxf(m2, __shfl_xor(m2, 32, 64));
        mx[rg] = m2;
      }
      bool ok = (mx[0] - mreg[0] <= 11.f) && (mx[1] - mreg[1] <= 11.f);
      if (!__all(ok)) {
#pragma unroll
        for (int rg = 0; rg < 2; rg++) {
          float mn = fmaxf(mreg[rg], mx[rg]);
          float fac = exp2f(mreg[rg] - mn);
          lreg[rg] *= fac;
          float fq[4];
#pragma unroll
          for (int r = 0; r < 4; r++) fq[r] = __shfl(fac, gq * 4 + r, 64);
#pragma unroll
          for (int nd = 0; nd < 8; nd++)
#pragma unroll
            for (int r = 0; r < 4; r++) oacc[rg][nd][r] *= fq[r];
          mreg[rg] = mn;
        }
      }
#pragma unroll
      for (int rg = 0; rg < 2; rg++) {
        float p[4][4];
        float rs = 0.f;
#pragma unroll
        for (int s = 0; s < 4; s++)
#pragma unroll
          for (int r = 0; r < 4; r++) {
            p[s][r] = exp2f(sacc[rg][s][r] - mreg[rg]);
            rs += p[s][r];
          }
        rs += __shfl_xor(rs, 16, 64);
        rs += __shfl_xor(rs, 32, 64);
        lreg[rg] += rs;
#pragma unroll
        for (int s = 0; s < 4; s++) {
          u32 w0 = cvtpk(p[s][0], p[s][1]);
          u32 w1 = cvtpk(p[s][2], p[s][3]);
          int a = (rg * 2048 + c * 128 + s * 32 + gq * 8) ^ swz;
          *(uint2*)(plds + a) = make_uint2(w0, w1);
        }
      }
#pragma unroll
      for (int kc2 = 0; kc2 < 2; kc2++) {
        int a0 = (c * 128 + kc2 * 64 + gq * 16) ^ swz;
        bf16x8 pa0 = *(const bf16x8*)(plds + a0);
        bf16x8 pa1 = *(const bf16x8*)(plds + 2048 + a0);
#pragma unroll
        for (int nd = 0; nd < 8; nd++) {
          int vrow = nd * 16 + c;
          int av = (vrow * 128 + (kc2 * 32 + gq * 8) * 2) ^ ((vrow & 7) << 4);
          bf16x8 vfr = *(const bf16x8*)(Vt + av);
          oacc[0][nd] = __builtin_amdgcn_mfma_f32_16x16x32_bf16(pa0, vfr, oacc[0][nd], 0, 0, 0);
          oacc[1][nd] = __builtin_amdgcn_mfma_f32_16x16x32_bf16(pa1, vfr, oacc[1][nd], 0, 0, 0);
        }
      }
    }
    __syncthreads();
  }
  int b2 = bh >> 4, h2 = bh & 15;
#pragma unroll
  for (int rg = 0; rg < 2; rg++) {
    float linv = 1.f / lreg[rg];
    float inv[4];
#pragma unroll
    for (int r = 0; r < 4; r++) inv[r] = __shfl(linv, gq * 4 + r, 64);
#pragma unroll
    for (int nd = 0; nd < 8; nd++) {
#pragma unroll
      for (int r = 0; r < 4; r++) {
        size_t offo = ((size_t)(b2 * TSEQ + q0w + rg * 16 + gq * 4 + r)) * 2048 + h2 * 128 + nd * 16 + c;
        y[offo] = f2bf(oacc[rg][nd][r] * inv[r]);
      }
    }
  }
}

extern "C" void kernel_launch(void* const* d_in, const int* in_sizes, int n_in,
                              void* d_out, int out_size, void* d_ws, size_t ws_size,
                              hipStream_t stream) {
  (void)in_sizes; (void)n_in; (void)out_size; (void)ws_size;
  const float* x      = (const float*)d_in[0];
  const float* ve     = (const float*)d_in[1];
  const float* cosp   = (const float*)d_in[2];
  const float* sinp   = (const float*)d_in[3];
  const float* w_dkv  = (const float*)d_in[4];
  const float* w_ukv  = (const float*)d_in[5];
  const float* w_kr   = (const float*)d_in[6];
  const float* w_dq   = (const float*)d_in[7];
  const float* w_q    = (const float*)d_in[8];
  const float* w_cp   = (const float*)d_in[9];
  const float* w_vg   = (const float*)d_in[10];
  float* out = (float*)d_out;   // reference output dtype is float32

  char* ws = (char*)d_ws;
  size_t off = 0;
  auto alloc = [&](size_t bytes) -> char* {
    char* p = ws + off;
    off += (bytes + 255) & ~(size_t)255;
    return p;
  };
  u16* xb     = (u16*)alloc(4096ull * 2048 * 2);
  u16* wcatT  = (u16*)alloc(1664ull * 2048 * 2);  // rows: [0,768)=dkv, [768,1536)=dq, [1536,1600)=kr
  u16* wukvT  = (u16*)alloc(3072ull * 768 * 2);
  u16* wqT    = (u16*)alloc(2048ull * 768 * 2);
  u16* wcpT   = (u16*)alloc(2048ull * 2048 * 2);
  u16* catout = (u16*)alloc(4096ull * 1664 * 2);  // cols: [0,768)=ckv, [768,1536)=q1, [1536,1600)=kr
  u16* kvb    = (u16*)alloc(4096ull * 3072 * 2);
  float* gateb = (float*)alloc(4096ull * 16 * 4);
  u16* qfb    = (u16*)alloc(2ull * 16 * 2048 * 128 * 2);
  u16* kswb   = (u16*)alloc(32ull * 32 * 8192 * 2);
  u16* vswb   = (u16*)alloc(32ull * 32 * 8192 * 2);
  u16* yb = xb; // alias: x_bf dead after the cat GEMM

  // 1. prep: all transposes + x->bf16 + gate in ONE dispatch
  k_prep<<<dim3(15488), dim3(256), 0, stream>>>(x, w_dkv, w_dq, w_kr, w_ukv, w_q, w_cp, w_vg,
                                                xb, wcatT, wukvT, wqT, wcpT, gateb);

  // 2. projection GEMMs (BK=64): cat (x-projections), then fused {ukv | q+build_q}
  k_gemm128<u16><<<dim3(13, 32), dim3(256), 0, stream>>>(xb, 2048, wcatT, 2048, catout, 1664, 2048);
  k_gemm_dual<<<dim3(40, 32), dim3(256), 0, stream>>>(catout, wukvT, kvb, wqT, cosp, sinp, qfb);

  // 3. build k + v in ONE dispatch (emit pre-swizzled 16KB tile images)
  k_build_kv<<<dim3(2048), dim3(256), 0, stream>>>(kvb, catout + 1536, cosp, sinp, ve, gateb, kswb, vswb);

  // 4. attention -> y (aliases xb): 512 blocks x 4 waves x 32 rows/wave, CU-balanced
  k_attn<<<dim3(512), dim3(256), 0, stream>>>(qfb, kswb, vswb, yb);

  // 5. output projection (BK=64, f32 out -> d_out)
  k_gemm128<float><<<dim3(16, 32), dim3(256), 0, stream>>>(yb, 2048, wcpT, 2048, out, 2048, 2048);
}

// Round 20
// 287.678 us; speedup vs baseline: 1.8411x; 1.0245x over previous
//
#include <hip/hip_runtime.h>
#include <hip/hip_bf16.h>

typedef unsigned short u16;
typedef unsigned int u32;
typedef __bf16 bf16x8 __attribute__((ext_vector_type(8)));
typedef float f32x4 __attribute__((ext_vector_type(4)));
typedef u16 ushort8 __attribute__((ext_vector_type(8)));

#define TSEQ 2048
#define NHEAD 16

#define GLD16(gp, lp) __builtin_amdgcn_global_load_lds( \
    (__attribute__((address_space(1))) void*)(gp), \
    (__attribute__((address_space(3))) void*)(lp), 16, 0, 0)

static __device__ __forceinline__ float bf2f(u16 u) {
  unsigned int x = ((unsigned int)u) << 16;
  union { unsigned int i; float f; } c; c.i = x; return c.f;
}
static __device__ __forceinline__ u16 f2bf(float f) {
  union { float f; unsigned int i; } c; c.f = f;
  unsigned int x = c.i;
  unsigned int r = (x + 0x7FFFu + ((x >> 16) & 1u)) >> 16;
  return (u16)r;
}
static __device__ __forceinline__ void st_out(u16* p, float v) { *p = f2bf(v); }
static __device__ __forceinline__ void st_out(float* p, float v) { *p = v; }
static __device__ __forceinline__ u32 cvtpk(float lo, float hi) {
  u32 w;
  asm("v_cvt_pk_bf16_f32 %0, %1, %2" : "=v"(w) : "v"(lo), "v"(hi));
  return w;
}

// -------- PREP: all weight transposes + x conversion + gate in ONE dispatch (block-range switch) --------
__global__ __launch_bounds__(256) void k_prep(const float* __restrict__ x,
                                              const float* __restrict__ w_dkv, const float* __restrict__ w_dq,
                                              const float* __restrict__ w_kr, const float* __restrict__ w_ukv,
                                              const float* __restrict__ w_q, const float* __restrict__ w_cp,
                                              const float* __restrict__ w_vg,
                                              u16* __restrict__ xb,
                                              u16* __restrict__ wcatT, u16* __restrict__ wukvT,
                                              u16* __restrict__ wqT, u16* __restrict__ wcpT,
                                              float* __restrict__ gateb) {
  __shared__ float sm[32][33];
  int z = blockIdx.x;
  if (z >= 15232) { // ---- gate: 256 blocks ----
    int idx = (z - 15232) * 256 + threadIdx.x; // m*16 + h
    int m = idx >> 4, h = idx & 15;
    const float* xr = x + (size_t)m * 2048;
    float s = 0.f;
#pragma unroll
    for (int j = 0; j < 32; j++) s += xr[j] * w_vg[j * 16 + h];
    gateb[idx] = 2.f / (1.f + __expf(-s));
    return;
  }
  if (z >= 11136) { // ---- conv_x: 4096 blocks ----
    size_t i = ((size_t)(z - 11136) * 256 + threadIdx.x) * 8;
    float4 a = *(const float4*)(x + i);
    float4 b = *(const float4*)(x + i + 4);
    ushort8 o;
    o[0] = f2bf(a.x); o[1] = f2bf(a.y); o[2] = f2bf(a.z); o[3] = f2bf(a.w);
    o[4] = f2bf(b.x); o[5] = f2bf(b.y); o[6] = f2bf(b.z); o[7] = f2bf(b.w);
    *(ushort8*)(xb + i) = o;
    return;
  }
  // ---- weight transposes: 11136 blocks ----
  const float* src; u16* dst; int R, Cc, Rpad, bx, by;
  if (z < 1536)       { src = w_dkv; dst = wcatT;              R = 2048; Cc = 672;  Rpad = 2048; int l = z;        bx = l % 64; by = l / 64; }
  else if (z < 3072)  { src = w_dq;  dst = wcatT + 768 * 2048; R = 2048; Cc = 672;  Rpad = 2048; int l = z - 1536; bx = l % 64; by = l / 64; }
  else if (z < 3200)  { src = w_kr;  dst = wcatT + 1536 * 2048;R = 2048; Cc = 64;   Rpad = 2048; int l = z - 3072; bx = l % 64; by = l / 64; }
  else if (z < 5504)  { src = w_ukv; dst = wukvT;              R = 672;  Cc = 3072; Rpad = 768;  int l = z - 3200; bx = l % 24; by = l / 24; }
  else if (z < 7040)  { src = w_q;   dst = wqT;                R = 672;  Cc = 2048; Rpad = 768;  int l = z - 5504; bx = l % 24; by = l / 24; }
  else                { src = w_cp;  dst = wcpT;               R = 2048; Cc = 2048; Rpad = 2048; int l = z - 7040; bx = l % 64; by = l / 64; }
  int tx = threadIdx.x & 31, ty = threadIdx.x >> 5;
  int r0 = bx * 32, c0 = by * 32;
#pragma unroll
  for (int i = 0; i < 4; i++) {
    int r = r0 + ty + 8 * i;
    int c = c0 + tx;
    sm[ty + 8 * i][tx] = (r < R && c < Cc) ? src[(size_t)r * Cc + c] : 0.f;
  }
  __syncthreads();
#pragma unroll
  for (int i = 0; i < 4; i++) {
    int c = c0 + ty + 8 * i;
    dst[(size_t)c * Rpad + r0 + tx] = f2bf(sm[tx][ty + 8 * i]);
  }
}

// ---- 128x128 GEMM, BK=128 via four 32-col LDS panels (quarter barrier count), global_load_lds w16 ----
// Used for the K=2048 GEMMs (cat, out) whose grids cap at <=2 blocks/CU anyway -> 64KB LDS is free.
template <typename OT>
__global__ __launch_bounds__(256) void k_gemm128(const u16* __restrict__ A, int lda,
                                                 const u16* __restrict__ BT, int ldb,
                                                 OT* __restrict__ C, int ldc,
                                                 int K) {
  __shared__ __align__(16) u16 As[4][128 * 32];
  __shared__ __align__(16) u16 Bs[4][128 * 32];
  int t = threadIdx.x;
  int wid = t >> 6, lane = t & 63;
  int m0 = blockIdx.y * 128, n0 = blockIdx.x * 128;
  int c0 = wid * 2;
  int srow0 = c0 * 16 + (lane >> 2);
  int scol = (lane & 3) * 8;
  const u16* Ag0 = A + (size_t)(m0 + srow0) * lda + scol;
  const u16* Ag1 = A + (size_t)(m0 + srow0 + 16) * lda + scol;
  const u16* Bg0 = BT + (size_t)(n0 + srow0) * ldb + scol;
  const u16* Bg1 = BT + (size_t)(n0 + srow0 + 16) * ldb + scol;
  int wr = (wid >> 1) * 64, wc = (wid & 1) * 64;
  int fr = lane & 15, fo = (lane >> 4) * 8;
  f32x4 acc[4][4];
#pragma unroll
  for (int m = 0; m < 4; m++)
#pragma unroll
    for (int n = 0; n < 4; n++) acc[m][n] = (f32x4){0, 0, 0, 0};
  for (int k0 = 0; k0 < K; k0 += 128) {
#pragma unroll
    for (int p = 0; p < 4; p++) {
      GLD16(Ag0 + k0 + p * 32, &As[p][c0 * 512]);
      GLD16(Ag1 + k0 + p * 32, &As[p][c0 * 512 + 512]);
      GLD16(Bg0 + k0 + p * 32, &Bs[p][c0 * 512]);
      GLD16(Bg1 + k0 + p * 32, &Bs[p][c0 * 512 + 512]);
    }
    __syncthreads();
#pragma unroll
    for (int p = 0; p < 4; p++) {
      bf16x8 af[4], bf[4];
#pragma unroll
      for (int m = 0; m < 4; m++) af[m] = *(const bf16x8*)&As[p][(wr + m * 16 + fr) * 32 + fo];
#pragma unroll
      for (int n = 0; n < 4; n++) bf[n] = *(const bf16x8*)&Bs[p][(wc + n * 16 + fr) * 32 + fo];
#pragma unroll
      for (int m = 0; m < 4; m++)
#pragma unroll
        for (int n = 0; n < 4; n++)
          acc[m][n] = __builtin_amdgcn_mfma_f32_16x16x32_bf16(af[m], bf[n], acc[m][n], 0, 0, 0);
    }
    __syncthreads();
  }
  int cr = (lane >> 4) * 4, cc = lane & 15;
#pragma unroll
  for (int m = 0; m < 4; m++)
#pragma unroll
    for (int n = 0; n < 4; n++)
#pragma unroll
      for (int r = 0; r < 4; r++)
        st_out(&C[(size_t)(m0 + wr + m * 16 + cr + r) * ldc + n0 + wc + n * 16 + cc], acc[m][n][r]);
}

// ---------------- dual GEMM (BK=64 panels; 4-blocks/CU grid keeps 32KB LDS): kv | q+rope/rmsnorm ----------------
__global__ __launch_bounds__(256) void k_gemm_dual(const u16* __restrict__ catout,
                                                   const u16* __restrict__ wukvT,
                                                   u16* __restrict__ kvb,
                                                   const u16* __restrict__ wqT,
                                                   const float* __restrict__ cosp,
                                                   const float* __restrict__ sinp,
                                                   u16* __restrict__ qf) {
  __shared__ __align__(16) u16 As[2][128 * 32];
  __shared__ __align__(16) u16 Bs[2][128 * 32];
  int t = threadIdx.x;
  int wid = t >> 6, lane = t & 63;
  int bx = blockIdx.x;
  bool isq = (bx >= 24);
  int nx = isq ? bx - 24 : bx;
  int m0 = blockIdx.y * 128, n0 = nx * 128;
  const u16* A = isq ? catout + 768 : catout;
  const u16* BT = isq ? wqT : wukvT;
  int c0 = wid * 2;
  int srow0 = c0 * 16 + (lane >> 2);
  int scol = (lane & 3) * 8;
  const u16* Ag0 = A + (size_t)(m0 + srow0) * 1664 + scol;
  const u16* Ag1 = A + (size_t)(m0 + srow0 + 16) * 1664 + scol;
  const u16* Bg0 = BT + (size_t)(n0 + srow0) * 768 + scol;
  const u16* Bg1 = BT + (size_t)(n0 + srow0 + 16) * 768 + scol;
  int wr = (wid >> 1) * 64, wc = (wid & 1) * 64;
  int fr = lane & 15, fo = (lane >> 4) * 8;
  f32x4 acc[4][4];
#pragma unroll
  for (int m = 0; m < 4; m++)
#pragma unroll
    for (int n = 0; n < 4; n++) acc[m][n] = (f32x4){0, 0, 0, 0};
  for (int k0 = 0; k0 < 768; k0 += 64) {
#pragma unroll
    for (int p = 0; p < 2; p++) {
      GLD16(Ag0 + k0 + p * 32, &As[p][c0 * 512]);
      GLD16(Ag1 + k0 + p * 32, &As[p][c0 * 512 + 512]);
      GLD16(Bg0 + k0 + p * 32, &Bs[p][c0 * 512]);
      GLD16(Bg1 + k0 + p * 32, &Bs[p][c0 * 512 + 512]);
    }
    __syncthreads();
#pragma unroll
    for (int p = 0; p < 2; p++) {
      bf16x8 af[4], bf[4];
#pragma unroll
      for (int m = 0; m < 4; m++) af[m] = *(const bf16x8*)&As[p][(wr + m * 16 + fr) * 32 + fo];
#pragma unroll
      for (int n = 0; n < 4; n++) bf[n] = *(const bf16x8*)&Bs[p][(wc + n * 16 + fr) * 32 + fo];
#pragma unroll
      for (int m = 0; m < 4; m++)
#pragma unroll
        for (int n = 0; n < 4; n++)
          acc[m][n] = __builtin_amdgcn_mfma_f32_16x16x32_bf16(af[m], bf[n], acc[m][n], 0, 0, 0);
    }
    __syncthreads();
  }
  int cr = (lane >> 4) * 4, cc = lane & 15;
  if (!isq) {
#pragma unroll
    for (int m = 0; m < 4; m++)
#pragma unroll
      for (int n = 0; n < 4; n++)
#pragma unroll
        for (int r = 0; r < 4; r++)
          kvb[(size_t)(m0 + wr + m * 16 + cr + r) * 3072 + n0 + wc + n * 16 + cc] = f2bf(acc[m][n][r]);
    return;
  }
  int h = nx;
  int wch = wid & 1;
  int wrg = wid >> 1;
  if (wch == 1) {
#pragma unroll
    for (int m = 0; m < 4; m++)
#pragma unroll
      for (int r = 0; r < 4; r++) {
        int grow = m0 + wr + m * 16 + cr + r;
#pragma unroll
        for (int n = 0; n < 2; n++) {
          int i = n * 16 + cc;
          float cth = cosp[(size_t)grow * 32 + i];
          float sth = sinp[(size_t)grow * 32 + i];
          float x1 = acc[m][n][r], x2 = acc[m][n + 2][r];
          acc[m][n][r]     = x1 * cth + x2 * sth;
          acc[m][n + 2][r] = x2 * cth - x1 * sth;
        }
      }
  }
  float part[4][4];
#pragma unroll
  for (int m = 0; m < 4; m++)
#pragma unroll
    for (int r = 0; r < 4; r++) {
      float s2 = 0.f;
#pragma unroll
      for (int n = 0; n < 4; n++) s2 += acc[m][n][r] * acc[m][n][r];
#pragma unroll
      for (int o = 1; o < 16; o <<= 1) s2 += __shfl_xor(s2, o, 64);
      part[m][r] = s2;
    }
  float* xs = (float*)&As[0][0];
  if (cc == 0) {
#pragma unroll
    for (int m = 0; m < 4; m++)
#pragma unroll
      for (int r = 0; r < 4; r++)
        xs[(wrg * 2 + wch) * 64 + m * 16 + cr + r] = part[m][r];
  }
  __syncthreads();
#pragma unroll
  for (int m = 0; m < 4; m++)
#pragma unroll
    for (int r = 0; r < 4; r++) {
      int lrow = m * 16 + cr + r;
      float tot = part[m][r] + xs[(wrg * 2 + (wch ^ 1)) * 64 + lrow];
      float rms = rsqrtf(tot * (1.f / 128.f) + 1.1920929e-7f) * 0.1275174245f;
      int grow = m0 + wr + lrow;
      int b2 = grow >> 11, tt = grow & 2047;
      size_t base = (((size_t)(b2 * NHEAD + h)) * TSEQ + tt) * 128 + wch * 64;
#pragma unroll
      for (int n = 0; n < 4; n++)
        qf[base + n * 16 + cc] = f2bf(acc[m][n][r] * rms);
    }
}

// ---------------- build K and V in one dispatch -> swizzled tile images [bh][tile][16KB] ----------------
__global__ __launch_bounds__(256) void k_build_kv(const u16* __restrict__ kv, const u16* __restrict__ kr,
                                                  const float* __restrict__ cosp, const float* __restrict__ sinp,
                                                  const float* __restrict__ ve, const float* __restrict__ gate,
                                                  u16* __restrict__ ksw, u16* __restrict__ vsw) {
  __shared__ __align__(16) char smraw[16384];
  int tid = threadIdx.x;
  if (blockIdx.x < 1024) {
    // ---- build K ----
    u16* sm = (u16*)smraw;
    int wid = tid >> 6, lane = tid & 63;
    int bh = blockIdx.x >> 5, tile = blockIdx.x & 31;
    int b = bh >> 4, h = bh & 15;
    int d0 = lane * 2;
    for (int rr = 0; rr < 16; rr++) {
      int row = wid * 16 + rr;
      int t = tile * 64 + row;
      int m = b * TSEQ + t;
      float v[2];
#pragma unroll
      for (int e = 0; e < 2; e++) {
        int d = d0 + e;
        float val;
        if (d < 64) {
          val = bf2f(kv[(size_t)m * 3072 + h * 192 + d]);
        } else {
          int dd = d - 64, i = dd & 31;
          float c = cosp[m * 32 + i], s = sinp[m * 32 + i];
          float x1 = bf2f(kr[(size_t)m * 1664 + i]), x2 = bf2f(kr[(size_t)m * 1664 + 32 + i]);
          val = (dd < 32) ? (x1 * c + x2 * s) : (x2 * c - x1 * s);
        }
        v[e] = val;
      }
      float ss = v[0] * v[0] + v[1] * v[1];
#pragma unroll
      for (int o = 1; o < 64; o <<= 1) ss += __shfl_xor(ss, o, 64);
      float rms = rsqrtf(ss * (1.f / 128.f) + 1.1920929e-7f);
      int a = (row * 256 + d0 * 2) ^ ((row & 7) << 4);
      sm[a >> 1] = f2bf(v[0] * rms);
      sm[(a >> 1) + 1] = f2bf(v[1] * rms);
    }
    __syncthreads();
    u16* dst = ksw + ((size_t)(bh * 32 + tile)) * 8192 + tid * 32;
    const u16* src = sm + tid * 32;
#pragma unroll
    for (int j = 0; j < 4; j++)
      *(ushort8*)(dst + j * 8) = *(const ushort8*)(src + j * 8);
  } else {
    // ---- build V ----
    char* sm = smraw;
    int bxv = blockIdx.x - 1024;
    int bh = bxv >> 5, tile = bxv & 31;
    int t0 = tile * 64;
    int b = bh >> 4, h = bh & 15;
    int tt = tid >> 2, dp = (tid & 3) * 32;
    int m = b * TSEQ + t0 + tt;
    float g = gate[m * 16 + h];
    const u16* kvp = kv + (size_t)m * 3072 + h * 192 + 64 + dp;
    const float* vep = ve + (size_t)m * 2048 + h * 128 + dp;
    ushort8 kvv[4];
    float4 vev[8];
#pragma unroll
    for (int u = 0; u < 4; u++) kvv[u] = *(const ushort8*)(kvp + u * 8);
#pragma unroll
    for (int u = 0; u < 8; u++) vev[u] = *(const float4*)(vep + u * 4);
#pragma unroll
    for (int j = 0; j < 32; j++) {
      float vvf = ((const float*)&vev[j >> 2])[j & 3];
      float v = bf2f(kvv[j >> 3][j & 7]) + g * vvf;
      int row = dp + j;
      int a = row * 128 + tt * 2;
      *(u16*)(sm + (a ^ ((row & 7) << 4))) = f2bf(v);
    }
    __syncthreads();
    u16* dst = vsw + ((size_t)(bh * 32 + tile)) * 8192 + tid * 32;
    const u16* src = (const u16*)sm + tid * 32;
#pragma unroll
    for (int j = 0; j < 4; j++)
      *(ushort8*)(dst + j * 8) = *(const ushort8*)(src + j * 8);
  }
}

// ---------------- flash attention v2: 128-row blocks, 32 q-rows/wave, staged K/V, balanced qb ----------------
__global__ __launch_bounds__(256, 2) void k_attn(const u16* __restrict__ qf, const u16* __restrict__ ksw,
                                                 const u16* __restrict__ vsw, u16* __restrict__ y) {
  __shared__ __align__(16) u16 kvbuf[2][2][8192]; // [buf][K=0/V=1][16KB]
  __shared__ __align__(16) char plds_all[4][4096]; // per wave: P [32 q][64 k] bf16, XOR-swizzled
  int tid = threadIdx.x, wid = tid >> 6, lane = tid & 63;
  int gq = lane >> 4, c = lane & 15;
  int task = (blockIdx.x & 7) * 64 + (blockIdx.x >> 3); // 512 blocks, XCD-chunked
  int bh = task >> 4;
  int tq = task & 15;
  int qb = ((task >> 5) & 1) ? tq : 15 - tq; // complementary pairing: blocks i,i+256 -> qb x,15-x (same CU)
  int nt = 2 * qb + 2;
  int q0w = qb * 128 + wid * 32;        // this wave's 32-row base
  const u16* qp = qf + (size_t)bh * TSEQ * 128;
  const u16* kswb = ksw + (size_t)bh * 32 * 8192;
  const u16* vswb = vsw + (size_t)bh * 32 * 8192;
  char* plds = plds_all[wid];
  int swz = (c & 7) << 4;
  bf16x8 qfr[2][4];
#pragma unroll
  for (int rg = 0; rg < 2; rg++)
#pragma unroll
    for (int kc = 0; kc < 4; kc++)
      qfr[rg][kc] = *(const bf16x8*)(qp + (size_t)(q0w + rg * 16 + c) * 128 + kc * 32 + gq * 8);
  f32x4 oacc[2][8];
#pragma unroll
  for (int rg = 0; rg < 2; rg++)
#pragma unroll
    for (int nd = 0; nd < 8; nd++) oacc[rg][nd] = (f32x4){0, 0, 0, 0};
  float mreg[2] = {-1e30f, -1e30f}, lreg[2] = {0.f, 0.f};
  int chunk = wid * 4;
#pragma unroll
  for (int j = 0; j < 4; j++) {
    GLD16(kswb + (chunk + j) * 512 + lane * 8, &kvbuf[0][0][(chunk + j) * 512]);
    GLD16(vswb + (chunk + j) * 512 + lane * 8, &kvbuf[0][1][(chunk + j) * 512]);
  }
  __syncthreads();
  for (int it = 0; it < nt; it++) {
    int cur = it & 1;
    if (it + 1 < nt) {
      const u16* kt = kswb + (size_t)(it + 1) * 8192;
      const u16* vt = vswb + (size_t)(it + 1) * 8192;
#pragma unroll
      for (int j = 0; j < 4; j++) {
        GLD16(kt + (chunk + j) * 512 + lane * 8, &kvbuf[cur ^ 1][0][(chunk + j) * 512]);
        GLD16(vt + (chunk + j) * 512 + lane * 8, &kvbuf[cur ^ 1][1][(chunk + j) * 512]);
      }
    }
    int kt0 = it * 64;
    if (kt0 <= q0w + 31) { // wave-uniform skip of fully-masked tiles
      const char* Kt = (const char*)kvbuf[cur][0];
      const char* Vt = (const char*)kvbuf[cur][1];
      bool maskit = (kt0 + 63 > q0w);
      f32x4 sacc[2][4];
#pragma unroll
      for (int rg = 0; rg < 2; rg++)
#pragma unroll
        for (int s = 0; s < 4; s++) sacc[rg][s] = (f32x4){0, 0, 0, 0};
#pragma unroll
      for (int s = 0; s < 4; s++) {
        int row = s * 16 + c;
#pragma unroll
        for (int kc = 0; kc < 4; kc++) {
          int a = (row * 256 + (kc * 32 + gq * 8) * 2) ^ ((row & 7) << 4);
          bf16x8 kfr = *(const bf16x8*)(Kt + a);
          sacc[0][s] = __builtin_amdgcn_mfma_f32_16x16x32_bf16(kfr, qfr[0][kc], sacc[0][s], 0, 0, 0);
          sacc[1][s] = __builtin_amdgcn_mfma_f32_16x16x32_bf16(kfr, qfr[1][kc], sacc[1][s], 0, 0, 0);
        }
      }
      if (maskit) {
#pragma unroll
        for (int rg = 0; rg < 2; rg++) {
          int qrow = q0w + rg * 16 + c;
#pragma unroll
          for (int s = 0; s < 4; s++)
#pragma unroll
            for (int r = 0; r < 4; r++) {
              int key = kt0 + s * 16 + gq * 4 + r;
              sacc[rg][s][r] = (key <= qrow) ? sacc[rg][s][r] : -3e38f;
            }
        }
      }
      float mx[2];
#pragma unroll
      for (int rg = 0; rg < 2; rg++) {
        float m2 = sacc[rg][0][0];
#pragma unroll
        for (int s = 0; s < 4; s++)
#pragma unroll
          for (int r = 0; r < 4; r++) m2 = fmaxf(m2, sacc[rg][s][r]);
        m2 = fmaxf(m2, __shfl_xor(m2, 16, 64));
        m2 = fmaxf(m2, __shfl_xor(m2, 32, 64));
        mx[rg] = m2;
      }
      bool ok = (mx[0] - mreg[0] <= 11.f) && (mx[1] - mreg[1] <= 11.f);
      if (!__all(ok)) {
#pragma unroll
        for (int rg = 0; rg < 2; rg++) {
          float mn = fmaxf(mreg[rg], mx[rg]);
          float fac = exp2f(mreg[rg] - mn);
          lreg[rg] *= fac;
          float fq[4];
#pragma unroll
          for (int r = 0; r < 4; r++) fq[r] = __shfl(fac, gq * 4 + r, 64);
#pragma unroll
          for (int nd = 0; nd < 8; nd++)
#pragma unroll
            for (int r = 0; r < 4; r++) oacc[rg][nd][r] *= fq[r];
          mreg[rg] = mn;
        }
      }
#pragma unroll
      for (int rg = 0; rg < 2; rg++) {
        float p[4][4];
        float rs = 0.f;
#pragma unroll
        for (int s = 0; s < 4; s++)
#pragma unroll
          for (int r = 0; r < 4; r++) {
            p[s][r] = exp2f(sacc[rg][s][r] - mreg[rg]);
            rs += p[s][r];
          }
        rs += __shfl_xor(rs, 16, 64);
        rs += __shfl_xor(rs, 32, 64);
        lreg[rg] += rs;
#pragma unroll
        for (int s = 0; s < 4; s++) {
          u32 w0 = cvtpk(p[s][0], p[s][1]);
          u32 w1 = cvtpk(p[s][2], p[s][3]);
          int a = (rg * 2048 + c * 128 + s * 32 + gq * 8) ^ swz;
          *(uint2*)(plds + a) = make_uint2(w0, w1);
        }
      }
#pragma unroll
      for (int kc2 = 0; kc2 < 2; kc2++) {
        int a0 = (c * 128 + kc2 * 64 + gq * 16) ^ swz;
        bf16x8 pa0 = *(const bf16x8*)(plds + a0);
        bf16x8 pa1 = *(const bf16x8*)(plds + 2048 + a0);
#pragma unroll
        for (int nd = 0; nd < 8; nd++) {
          int vrow = nd * 16 + c;
          int av = (vrow * 128 + (kc2 * 32 + gq * 8) * 2) ^ ((vrow & 7) << 4);
          bf16x8 vfr = *(const bf16x8*)(Vt + av);
          oacc[0][nd] = __builtin_amdgcn_mfma_f32_16x16x32_bf16(pa0, vfr, oacc[0][nd], 0, 0, 0);
          oacc[1][nd] = __builtin_amdgcn_mfma_f32_16x16x32_bf16(pa1, vfr, oacc[1][nd], 0, 0, 0);
        }
      }
    }
    __syncthreads();
  }
  int b2 = bh >> 4, h2 = bh & 15;
#pragma unroll
  for (int rg = 0; rg < 2; rg++) {
    float linv = 1.f / lreg[rg];
    float inv[4];
#pragma unroll
    for (int r = 0; r < 4; r++) inv[r] = __shfl(linv, gq * 4 + r, 64);
#pragma unroll
    for (int nd = 0; nd < 8; nd++) {
#pragma unroll
      for (int r = 0; r < 4; r++) {
        size_t offo = ((size_t)(b2 * TSEQ + q0w + rg * 16 + gq * 4 + r)) * 2048 + h2 * 128 + nd * 16 + c;
        y[offo] = f2bf(oacc[rg][nd][r] * inv[r]);
      }
    }
  }
}

extern "C" void kernel_launch(void* const* d_in, const int* in_sizes, int n_in,
                              void* d_out, int out_size, void* d_ws, size_t ws_size,
                              hipStream_t stream) {
  (void)in_sizes; (void)n_in; (void)out_size; (void)ws_size;
  const float* x      = (const float*)d_in[0];
  const float* ve     = (const float*)d_in[1];
  const float* cosp   = (const float*)d_in[2];
  const float* sinp   = (const float*)d_in[3];
  const float* w_dkv  = (const float*)d_in[4];
  const float* w_ukv  = (const float*)d_in[5];
  const float* w_kr   = (const float*)d_in[6];
  const float* w_dq   = (const float*)d_in[7];
  const float* w_q    = (const float*)d_in[8];
  const float* w_cp   = (const float*)d_in[9];
  const float* w_vg   = (const float*)d_in[10];
  float* out = (float*)d_out;   // reference output dtype is float32

  char* ws = (char*)d_ws;
  size_t off = 0;
  auto alloc = [&](size_t bytes) -> char* {
    char* p = ws + off;
    off += (bytes + 255) & ~(size_t)255;
    return p;
  };
  u16* xb     = (u16*)alloc(4096ull * 2048 * 2);
  u16* wcatT  = (u16*)alloc(1664ull * 2048 * 2);  // rows: [0,768)=dkv, [768,1536)=dq, [1536,1600)=kr
  u16* wukvT  = (u16*)alloc(3072ull * 768 * 2);
  u16* wqT    = (u16*)alloc(2048ull * 768 * 2);
  u16* wcpT   = (u16*)alloc(2048ull * 2048 * 2);
  u16* catout = (u16*)alloc(4096ull * 1664 * 2);  // cols: [0,768)=ckv, [768,1536)=q1, [1536,1600)=kr
  u16* kvb    = (u16*)alloc(4096ull * 3072 * 2);
  float* gateb = (float*)alloc(4096ull * 16 * 4);
  u16* qfb    = (u16*)alloc(2ull * 16 * 2048 * 128 * 2);
  u16* kswb   = (u16*)alloc(32ull * 32 * 8192 * 2);
  u16* vswb   = (u16*)alloc(32ull * 32 * 8192 * 2);
  u16* yb = xb; // alias: x_bf dead after the cat GEMM

  // 1. prep: all transposes + x->bf16 + gate in ONE dispatch
  k_prep<<<dim3(15488), dim3(256), 0, stream>>>(x, w_dkv, w_dq, w_kr, w_ukv, w_q, w_cp, w_vg,
                                                xb, wcatT, wukvT, wqT, wcpT, gateb);

  // 2. projection GEMMs: cat (BK=128), then fused {ukv | q+build_q} (BK=64)
  k_gemm128<u16><<<dim3(13, 32), dim3(256), 0, stream>>>(xb, 2048, wcatT, 2048, catout, 1664, 2048);
  k_gemm_dual<<<dim3(40, 32), dim3(256), 0, stream>>>(catout, wukvT, kvb, wqT, cosp, sinp, qfb);

  // 3. build k + v in ONE dispatch (emit pre-swizzled 16KB tile images)
  k_build_kv<<<dim3(2048), dim3(256), 0, stream>>>(kvb, catout + 1536, cosp, sinp, ve, gateb, kswb, vswb);

  // 4. attention -> y (aliases xb): 512 blocks x 4 waves x 32 rows/wave, CU-balanced
  k_attn<<<dim3(512), dim3(256), 0, stream>>>(qfb, kswb, vswb, yb);

  // 5. output projection (BK=128, f32 out -> d_out)
  k_gemm128<float><<<dim3(16, 32), dim3(256), 0, stream>>>(yb, 2048, wcpT, 2048, out, 2048, 2048);
}